// Round 22
// baseline (145.705 us; speedup 1.0000x reference)
//
#include <hip/hip_runtime.h>
#include <hip/hip_fp16.h>
#include <math.h>

#define B_ 4
#define T_ 1024
#define D_ 512
#define H_ 8
#define HD_ 64
#define KN 30
#define ED_ 128
#define DFF_ 2048
#define M_ 4096   // B*T
#define BH_ 32

typedef _Float16 f16;
typedef __attribute__((ext_vector_type(8))) _Float16 f16x8;
typedef __attribute__((ext_vector_type(4))) _Float16 f16x4;
typedef __attribute__((ext_vector_type(4))) float f32x4;

#define MFMA16 __builtin_amdgcn_mfma_f32_16x16x32_f16
#define LOG2E 1.44269504088896f

__device__ __forceinline__ f16x8 ld8(const f16* p){ return *reinterpret_cast<const f16x8*>(p); }

__device__ __forceinline__ void gld16(const void* g, void* l){
  __builtin_amdgcn_global_load_lds((const __attribute__((address_space(1))) void*)g,
                                   (__attribute__((address_space(3))) void*)l, 16, 0, 0);
}

// ---------------- fused prep: 9x fp32->f16 convert + bias prep --------------
struct CvtJobs {
  const float* s[9];
  f16* d[9];
  int start[10];   // cumulative block starts; each block = 256 float4s
};

// blocks [0, cvtBlocks): convert; blocks [cvtBlocks, +2048): biasprep.
// biasT layout (unchanged): for (bi,tb,c8,ws4,qg,l16,l4), 8 f16 at u*8 =
// [step0 j0..3 | step1 j0..3] of scaled bias[t=tb*32+qg*16+l16]
// [s=c8*128+ws4*32+step*16+l4*4+j].  (attn re-indexes for 256-chunks.)
__global__ __launch_bounds__(256) void prep_kernel(
    CvtJobs J, int cvtBlocks,
    const float* __restrict__ bias, const int* __restrict__ mask,
    const float* __restrict__ tsc, f16* __restrict__ biasT)
{
  if (blockIdx.x < cvtBlocks){
    const int blk = blockIdx.x;
    int j = 0;
    while (j < 8 && blk >= J.start[j+1]) ++j;
    const int i = (blk - J.start[j])*256 + threadIdx.x;
    float4 v = reinterpret_cast<const float4*>(J.s[j])[i];
    union { f16 h[4]; ushort4 u; } o;
    o.h[0]=(f16)v.x; o.h[1]=(f16)v.y; o.h[2]=(f16)v.z; o.h[3]=(f16)v.w;
    reinterpret_cast<ushort4*>(J.d[j])[i] = o.u;
    return;
  }
  const int u = (blockIdx.x - cvtBlocks)*256 + threadIdx.x;   // 524288 threads
  const int l4 = u & 3, l16 = (u >> 2) & 15, qg = (u >> 6) & 1;
  const int ws = (u >> 7) & 3, c = (u >> 9) & 7, tb = (u >> 12) & 31, bi = u >> 17;
  const float s = exp2f(-2.0f*tanhf(tsc[0]))*LOG2E;  // log2e / 4^tanh(t)
  const int t  = tb*32 + qg*16 + l16;
  const int s0 = c*128 + ws*32 + l4*4;
  const float* bp = bias + ((size_t)bi*T_ + t)*T_ + s0;
  const int*   mp = mask + bi*T_ + s0;
  union { f16 h[8]; f16x8 v8; } o;
#pragma unroll
  for (int st = 0; st < 2; ++st){
    float4 v = *reinterpret_cast<const float4*>(bp + st*16);
    int4  mm = *reinterpret_cast<const int4*>(mp + st*16);
    float x[4] = {v.x,v.y,v.z,v.w};
    int  m4[4] = {mm.x,mm.y,mm.z,mm.w};
#pragma unroll
    for (int j = 0; j < 4; ++j){
      float tv = (x[j] + (m4[j] ? 0.f : -60000.f))*s;
      o.h[st*4 + j] = (f16)fmaxf(tv, -60000.f);
    }
  }
  *reinterpret_cast<f16x8*>(biasT + (size_t)u*8) = o.v8;
}

// =============== staged MFMA GEMM: C = X @ W.T, BK=64, XOR-swizzled =========
// Ping-pong LDS + counted vmcnt(8). EPI 1: gelu; EPI 2: raw f16.
template<int EPI>
__global__ __launch_bounds__(256,2) void gemm_tile(
    const f16* __restrict__ X, const f16* __restrict__ W,
    const float* __restrict__ bias, void* __restrict__ outp,
    int Kd, int ldo, int nbN)
{
  __shared__ f16 As[2*8192];   // 2 x [128][64]
  __shared__ f16 Bs[2*8192];
  const int nwg = gridDim.x;
  const int bid = blockIdx.x;
  const int swz = (bid & 7)*(nwg >> 3) + (bid >> 3);
  const int mb = swz / nbN, nb = swz - mb*nbN;
  const int rb = mb*128, cb = nb*128;
  const int tid = threadIdx.x;
  const int w = tid >> 6, lane = tid & 63;
  const int l16 = lane & 15, l4 = lane >> 4;
  const int wr = w >> 1, wc = w & 1;
  const int key = l16 & 7;

  auto stage = [&](int ph, int slot){
#pragma unroll
    for (int i = 0; i < 4; ++i){
      const int cidx = i*256 + w*64 + lane;
      const int r = cidx >> 3, p = cidx & 7;
      gld16(X + (size_t)(rb + r)*Kd + ph*64 + ((p ^ (r & 7)) << 3),
            &As[slot*8192 + (i*256 + w*64)*8]);
      gld16(W + (size_t)(cb + r)*Kd + ph*64 + ((p ^ (r & 7)) << 3),
            &Bs[slot*8192 + (i*256 + w*64)*8]);
    }
  };

  f32x4 acc[4][4];
#pragma unroll
  for (int m = 0; m < 4; ++m)
#pragma unroll
    for (int n = 0; n < 4; ++n) acc[m][n] = (f32x4){0.f,0.f,0.f,0.f};

  const int nPh = Kd >> 6;
  stage(0, 0);
  for (int ph = 0; ph < nPh; ++ph){
    if (ph < nPh-1) stage(ph+1, (ph+1)&1);
    if (ph < nPh-1) asm volatile("s_waitcnt vmcnt(8)" ::: "memory");
    else            asm volatile("s_waitcnt vmcnt(0)" ::: "memory");
    __builtin_amdgcn_sched_barrier(0);
    __builtin_amdgcn_s_barrier();
    __builtin_amdgcn_sched_barrier(0);
    const int base = (ph&1)*8192;
#pragma unroll
    for (int kk = 0; kk < 2; ++kk){
      f16x8 a[4], b[4];
#pragma unroll
      for (int m = 0; m < 4; ++m)
        a[m] = ld8(&As[base + (wr*64 + m*16 + l16)*64 + (((kk*4 + l4) ^ key) << 3)]);
#pragma unroll
      for (int n = 0; n < 4; ++n)
        b[n] = ld8(&Bs[base + (wc*64 + n*16 + l16)*64 + (((kk*4 + l4) ^ key) << 3)]);
#pragma unroll
      for (int m = 0; m < 4; ++m)
#pragma unroll
        for (int n = 0; n < 4; ++n)
          acc[m][n] = MFMA16(a[m], b[n], acc[m][n], 0,0,0);
    }
    __builtin_amdgcn_s_barrier();   // readers of slot (ph&1) done
  }

#pragma unroll
  for (int n = 0; n < 4; ++n){
    const int col = cb + wc*64 + n*16 + l16;
    const float bv = bias[col];
#pragma unroll
    for (int m = 0; m < 4; ++m){
#pragma unroll
      for (int j = 0; j < 4; ++j){
        const int row = rb + wr*64 + m*16 + l4*4 + j;
        float v = acc[m][n][j] + bv;
        if (EPI == 1) v = 0.5f*v*(1.0f + erff(v*0.70710678118654752f));
        ((f16*)outp)[(size_t)row*ldo + col] = (f16)v;
      }
    }
  }
}

// =============== 128x64-tile GEMM, BK=64, pipelined, split-K ================
template<int EPI, int KS>
__global__ __launch_bounds__(256,3) void gemm_n64(
    const f16* __restrict__ X, const f16* __restrict__ W,
    const float* __restrict__ bias, void* __restrict__ outp,
    int Kd, int ldo, int nbN)
{
  __shared__ f16 As[2*8192];   // 2 x [128][64]
  __shared__ f16 Bs[2*4096];   // 2 x [64][64]
  const int nwg = gridDim.x;
  const int bid = blockIdx.x;
  const int swz = (bid & 7)*(nwg >> 3) + (bid >> 3);
  const int per = nwg / KS;
  const int ks = swz / per;
  const int r2 = swz - ks*per;
  const int mb = r2 / nbN, nb = r2 - mb*nbN;
  const int rb = mb*128, cb = nb*64;
  const int kOff = ks*(Kd/KS);
  const int tid = threadIdx.x;
  const int w = tid >> 6, lane = tid & 63;
  const int l16 = lane & 15, l4 = lane >> 4;
  const int wr = w >> 1, wc = w & 1;
  const int key = l16 & 7;

  auto stage = [&](int ph, int slot){
#pragma unroll
    for (int i = 0; i < 4; ++i){
      const int cidx = i*256 + w*64 + lane;
      const int r = cidx >> 3, p = cidx & 7;
      gld16(X + (size_t)(rb + r)*Kd + kOff + ph*64 + ((p ^ (r & 7)) << 3),
            &As[slot*8192 + (i*256 + w*64)*8]);
    }
#pragma unroll
    for (int i = 0; i < 2; ++i){
      const int cidx = i*256 + w*64 + lane;
      const int r = cidx >> 3, p = cidx & 7;
      gld16(W + (size_t)(cb + r)*Kd + kOff + ph*64 + ((p ^ (r & 7)) << 3),
            &Bs[slot*4096 + (i*256 + w*64)*8]);
    }
  };

  f32x4 acc[4][2];
#pragma unroll
  for (int m = 0; m < 4; ++m)
#pragma unroll
    for (int n = 0; n < 2; ++n) acc[m][n] = (f32x4){0.f,0.f,0.f,0.f};

  const int nPh = (Kd/KS) >> 6;
  stage(0, 0);
  for (int ph = 0; ph < nPh; ++ph){
    if (ph < nPh-1) stage(ph+1, (ph+1)&1);
    if (ph < nPh-1) asm volatile("s_waitcnt vmcnt(6)" ::: "memory");
    else            asm volatile("s_waitcnt vmcnt(0)" ::: "memory");
    __builtin_amdgcn_sched_barrier(0);
    __builtin_amdgcn_s_barrier();
    __builtin_amdgcn_sched_barrier(0);
    const int baseA = (ph&1)*8192, baseB = (ph&1)*4096;
#pragma unroll
    for (int kk = 0; kk < 2; ++kk){
      f16x8 a[4], b[2];
#pragma unroll
      for (int m = 0; m < 4; ++m)
        a[m] = ld8(&As[baseA + (wr*64 + m*16 + l16)*64 + (((kk*4 + l4) ^ key) << 3)]);
#pragma unroll
      for (int n = 0; n < 2; ++n)
        b[n] = ld8(&Bs[baseB + (wc*32 + n*16 + l16)*64 + (((kk*4 + l4) ^ key) << 3)]);
#pragma unroll
      for (int m = 0; m < 4; ++m)
#pragma unroll
        for (int n = 0; n < 2; ++n)
          acc[m][n] = MFMA16(a[m], b[n], acc[m][n], 0,0,0);
    }
    __builtin_amdgcn_s_barrier();
  }

#pragma unroll
  for (int n = 0; n < 2; ++n){
    const int col = cb + wc*32 + n*16 + l16;
    const float bv = (ks == 0) ? bias[col] : 0.f;
#pragma unroll
    for (int m = 0; m < 4; ++m){
#pragma unroll
      for (int j = 0; j < 4; ++j){
        const int row = rb + wr*64 + m*16 + l4*4 + j;
        float v = acc[m][n][j] + bv;
        if (EPI == 1) v = 0.5f*v*(1.0f + erff(v*0.70710678118654752f));
        ((f16*)outp)[(size_t)ks*M_*ldo + (size_t)row*ldo + col] = (f16)v;
      }
    }
  }
}

// =============== batched QKV projection, BK=64, pipelined ===================
__global__ __launch_bounds__(256,2) void qkv_tile(
    const f16* __restrict__ hV, const f16* __restrict__ kI, const f16* __restrict__ vI,
    const f16* __restrict__ Wq, const f16* __restrict__ Wk, const f16* __restrict__ Wv,
    const float* __restrict__ bq, const float* __restrict__ bk, const float* __restrict__ bv,
    const float* __restrict__ tsc,
    f16* __restrict__ qo, f16* __restrict__ ko, f16* __restrict__ vT)
{
  __shared__ f16 As[2*8192];
  __shared__ f16 Bs[2*8192];
  const int bid = blockIdx.x;
  const int swz = (bid & 7)*48 + (bid >> 3);
  const int g = swz >> 7;
  const int r = swz & 127;
  const int mb = r >> 2, nb = r & 3;
  const f16* X  = (g == 0) ? hV : ((g == 1) ? kI : vI);
  const f16* W  = (g == 0) ? Wq : ((g == 1) ? Wk : Wv);
  const float* bias = (g == 0) ? bq : ((g == 1) ? bk : bv);
  const int rb = mb*128, cb = nb*128;
  const int tid = threadIdx.x;
  const int w = tid >> 6, lane = tid & 63;
  const int l16 = lane & 15, l4 = lane >> 4;
  const int wr = w >> 1, wc = w & 1;
  const int key = l16 & 7;

  auto stage = [&](int ph, int slot){
#pragma unroll
    for (int i = 0; i < 4; ++i){
      const int cidx = i*256 + w*64 + lane;
      const int rr = cidx >> 3, p = cidx & 7;
      gld16(X + (size_t)(rb + rr)*D_ + ph*64 + ((p ^ (rr & 7)) << 3),
            &As[slot*8192 + (i*256 + w*64)*8]);
      gld16(W + (size_t)(cb + rr)*D_ + ph*64 + ((p ^ (rr & 7)) << 3),
            &Bs[slot*8192 + (i*256 + w*64)*8]);
    }
  };

  f32x4 acc[4][4];
#pragma unroll
  for (int m = 0; m < 4; ++m)
#pragma unroll
    for (int n = 0; n < 4; ++n) acc[m][n] = (f32x4){0.f,0.f,0.f,0.f};

  stage(0, 0);
#pragma unroll
  for (int ph = 0; ph < 8; ++ph){
    if (ph < 7) stage(ph+1, (ph+1)&1);
    if (ph < 7) asm volatile("s_waitcnt vmcnt(8)" ::: "memory");
    else        asm volatile("s_waitcnt vmcnt(0)" ::: "memory");
    __builtin_amdgcn_sched_barrier(0);
    __builtin_amdgcn_s_barrier();
    __builtin_amdgcn_sched_barrier(0);
    const int base = (ph&1)*8192;
#pragma unroll
    for (int kk = 0; kk < 2; ++kk){
      f16x8 a[4], b[4];
#pragma unroll
      for (int m = 0; m < 4; ++m)
        a[m] = ld8(&As[base + (wr*64 + m*16 + l16)*64 + (((kk*4 + l4) ^ key) << 3)]);
#pragma unroll
      for (int n = 0; n < 4; ++n)
        b[n] = ld8(&Bs[base + (wc*64 + n*16 + l16)*64 + (((kk*4 + l4) ^ key) << 3)]);
#pragma unroll
      for (int m = 0; m < 4; ++m)
#pragma unroll
        for (int n = 0; n < 4; ++n)
          acc[m][n] = MFMA16(a[m], b[n], acc[m][n], 0,0,0);
    }
    __builtin_amdgcn_s_barrier();
  }

  const float qs = exp2f(-2.0f*tanhf(tsc[0]))*LOG2E*0.125f;
  const float scale = (g == 0) ? qs : 1.0f;
  f16* out = (g == 0) ? qo : ko;
#pragma unroll
  for (int n = 0; n < 4; ++n){
    const int col = cb + wc*64 + n*16 + l16;
    const float bv = bias[col];
#pragma unroll
    for (int m = 0; m < 4; ++m){
#pragma unroll
      for (int j = 0; j < 4; ++j){
        const int row = rb + wr*64 + m*16 + l4*4 + j;
        const float v = (acc[m][n][j] + bv)*scale;
        if (g < 2){
          out[(size_t)row*D_ + col] = (f16)v;
        } else {
          const int b = row >> 10, t = row & (T_-1);
          const int h = col >> 6,  dl = col & (HD_-1);
          vT[(((size_t)b*H_ + h)*HD_ + dl)*T_ + t] = (f16)v;
        }
      }
    }
  }
}

// =============== fused attention (QBLK=32, 256-s chunks, 8 phases) ==========
// 8 waves: qg=w>>2 owns q-group, ws=w&3 owns s-subrange / d-cols.
// Chunks of 256 s halve the barrier count (4 QK + 4 PV phases, 2 barriers
// each). K/V chunk = 32 KB, ping-pong (64 KB) + Pc [32][256] (16 KB).
// Counted vmcnt(4) mid-loop. Bias fragments preloaded (biasT layout kept;
// re-indexed: c_old=2c+(ws>>1), ws_old=2(ws&1)+(step>>1), step_old=step&1).
__global__ __launch_bounds__(512,4) void attn_fused(
    const f16* __restrict__ q, const f16* __restrict__ k, const f16* __restrict__ vT,
    const f16* __restrict__ biasT, const int* __restrict__ eidx,
    f16* __restrict__ X2, float* __restrict__ gpart)
{
  __shared__ f16 Sb[2*16384];     // 64 KB: K/V 256-chunk double buffer
  __shared__ f16 Pc[32*256];      // 16 KB: P chunk [32 q][256 s]
  const int bid = blockIdx.x;
  const int swz = (bid & 7)*128 + (bid >> 3);   // XCD-contiguous
  const int bh = swz >> 5, tb = swz & 31;
  const int bi = bh >> 3, h = bh & 7;
  const int t0 = tb*32;
  const int tid = threadIdx.x, w = tid >> 6, lane = tid & 63;
  const int qg = w >> 2, ws = w & 3;
  const int l16 = lane & 15, l4 = lane >> 4;
  const int key = l16 & 7;

  // ---- Q fragments ----
  const f16* qp = q + (size_t)(bi*T_ + t0 + qg*16 + l16)*D_ + h*HD_ + l4*8;
  const f16x8 q0 = ld8(qp), q1 = ld8(qp + 32);
  // ---- bias fragments: biasT base excluding c_old/ws_old, preloaded ----
  const f16* bb0 = biasT + (size_t)(bi*32 + tb)*32768 + qg*512 + l16*32 + l4*8;
  f16x8 bfr[8];   // [c][shalf] -> bfr[c*2+shalf]
#pragma unroll
  for (int c = 0; c < 4; ++c)
#pragma unroll
    for (int sh = 0; sh < 2; ++sh)
      bfr[c*2+sh] = ld8(bb0 + (2*c + (ws >> 1))*4096 + (2*(ws & 1) + sh)*1024);
  // ---- gather tuples: each tid handles items of its own qg half ----
  const int tl = tid & 255;
  int ga_r, ga_kk, ga_id, gb_r = 0, gb_kk = 0, gb_id = -1;
  ga_r = tl/KN; ga_kk = tl - ga_r*KN;
  ga_id = eidx[((size_t)(bi*T_ + t0 + qg*16 + ga_r))*KN + ga_kk];
  if (tl + 256 < 16*KN){
    gb_r = (tl+256)/KN; gb_kk = (tl+256) - gb_r*KN;
    gb_id = eidx[((size_t)(bi*T_ + t0 + qg*16 + gb_r))*KN + gb_kk];
  }

  const f16* kg = k + (size_t)(bi*T_)*D_ + h*HD_;
  const f16* vg = vT + (size_t)bh*HD_*T_;

  auto stageK = [&](int c, int slot){
#pragma unroll
    for (int i = 0; i < 4; ++i){
      const int cidx = i*512 + w*64 + lane;
      const int r = cidx >> 3, p = cidx & 7;   // r 0..255, p 0..7
      gld16(kg + (size_t)(c*256 + r)*D_ + ((p ^ (r & 7)) << 3),
            &Sb[slot*16384 + (i*512 + w*64)*8]);
    }
  };
  auto stageV = [&](int sc, int slot){
#pragma unroll
    for (int i = 0; i < 4; ++i){
      const int cidx = i*512 + w*64 + lane;
      const int r = cidx >> 5, p = cidx & 31;  // r 0..63, p 0..31 (512B rows)
      gld16(vg + (size_t)r*T_ + sc*256 + ((p ^ (r & 7)) << 3),
            &Sb[slot*16384 + (i*512 + w*64)*8]);
    }
  };

  // ---- QK^T: 4 chunks of 256 s, ping-pong + counted vmcnt ----
  f32x4 acc[16];
  stageK(0, 0);
#pragma unroll
  for (int c = 0; c < 4; ++c){
    if (c < 3) stageK(c+1, (c+1)&1);
    if (c < 3) asm volatile("s_waitcnt vmcnt(4)" ::: "memory");
    else       asm volatile("s_waitcnt vmcnt(0)" ::: "memory");
    __builtin_amdgcn_sched_barrier(0);
    __builtin_amdgcn_s_barrier();
    __builtin_amdgcn_sched_barrier(0);
    const int base = (c&1)*16384;
#pragma unroll
    for (int step = 0; step < 4; ++step){
      const int rr = ws*64 + step*16 + l16;    // local s row in 256-chunk
      f32x4 a = {0.f,0.f,0.f,0.f};
      a = MFMA16(ld8(&Sb[base + rr*64 + ((l4 ^ key) << 3)]),       q0, a, 0,0,0);
      a = MFMA16(ld8(&Sb[base + rr*64 + (((4 + l4) ^ key) << 3)]), q1, a, 0,0,0);
#pragma unroll
      for (int j = 0; j < 4; ++j) a[j] += (float)bfr[c*2 + (step>>1)][(step&1)*4 + j];
      acc[c*4 + step] = a;
    }
    __builtin_amdgcn_s_barrier();   // readers of slot (c&1) done
  }

  // ---- softmax (stats overlay on idle Sb; sums redistributed via shfl) ----
  float* redf = (float*)Sb;         // [0..127]=max, [128..255]=sum
  float m = -3.4e38f;
#pragma unroll
  for (int c = 0; c < 16; ++c)
#pragma unroll
    for (int j = 0; j < 4; ++j) m = fmaxf(m, acc[c][j]);
  m = fmaxf(m, __shfl_xor(m, 16));
  m = fmaxf(m, __shfl_xor(m, 32));
  if (lane < 16) redf[(qg*4 + ws)*16 + lane] = m;
  __syncthreads();
  m = fmaxf(fmaxf(redf[(qg*4+0)*16 + l16], redf[(qg*4+1)*16 + l16]),
            fmaxf(redf[(qg*4+2)*16 + l16], redf[(qg*4+3)*16 + l16]));
  float l = 0.f;
#pragma unroll
  for (int c = 0; c < 16; ++c)
#pragma unroll
    for (int j = 0; j < 4; ++j){
      const float e = exp2f(acc[c][j] - m);
      l += e;
      acc[c][j] = e;                // acc now holds unnormalized P
    }
  l += __shfl_xor(l, 16);
  l += __shfl_xor(l, 32);
  if (lane < 16) redf[128 + (qg*4 + ws)*16 + lane] = l;
  __syncthreads();
  const float lrq = redf[128 + (qg*4+0)*16 + l16] + redf[128 + (qg*4+1)*16 + l16]
                  + redf[128 + (qg*4+2)*16 + l16] + redf[128 + (qg*4+3)*16 + l16];
  __syncthreads();                  // all lrq reads done before V staging clobbers
  const float lr_a = __shfl(lrq, ga_r);
  const float lr_b = __shfl(lrq, gb_r);

  // ---- PV: 4 chunks of 256 s; ping-pong; gather -> registers ----
  f32x4 oo0 = {0.f,0.f,0.f,0.f}, oo1 = oo0, oo2 = oo0, oo3 = oo0;
  float pva = 0.f, pvb = 0.f;
  stageV(0, 0);
#pragma unroll
  for (int sc = 0; sc < 4; ++sc){
    // write own P slice for chunk sc (rows qg*16.., s-local [ws*64,+64))
#pragma unroll
    for (int step = 0; step < 4; ++step){
      const int slb = ws*64 + step*16 + l4*4;
      f16x4 pp;
#pragma unroll
      for (int j = 0; j < 4; ++j) pp[j] = (f16)acc[sc*4 + step][j];
      *reinterpret_cast<f16x4*>(
          &Pc[(qg*16 + l16)*256 + (((slb >> 3) ^ key) << 3) + (slb & 7)]) = pp;
    }
    if (sc < 3) stageV(sc+1, (sc+1)&1);
    if (sc < 3) asm volatile("s_waitcnt vmcnt(4) lgkmcnt(0)" ::: "memory");
    else        asm volatile("s_waitcnt vmcnt(0) lgkmcnt(0)" ::: "memory");
    __builtin_amdgcn_sched_barrier(0);
    __builtin_amdgcn_s_barrier();
    __builtin_amdgcn_sched_barrier(0);
    const int base = (sc&1)*16384;
    const int vrow = (ws*16 + l16)*256;
#pragma unroll
    for (int grp = 0; grp < 8; ++grp){
      const int ch = (grp*4 + l4) ^ key;       // 16B chunk 0..31 in 512B row
      const f16x8 pa = ld8(&Pc[(qg*16 + l16)*256 + (ch << 3)]);
      const f16x8 vb = ld8(&Sb[base + vrow + (ch << 3)]);
      if ((grp & 3) == 0)      oo0 = MFMA16(pa, vb, oo0, 0,0,0);
      else if ((grp & 3) == 1) oo1 = MFMA16(pa, vb, oo1, 0,0,0);
      else if ((grp & 3) == 2) oo2 = MFMA16(pa, vb, oo2, 0,0,0);
      else                     oo3 = MFMA16(pa, vb, oo3, 0,0,0);
    }
    // edge gather capture (no VMEM stores inside the loop)
    if ((ga_id >> 8) == sc){
      const int r = qg*16 + ga_r;
      const int sl = ga_id & 255;
      pva = (float)Pc[r*256 + ((((sl >> 3) ^ (r & 7)) << 3) | (sl & 7))];
    }
    if (gb_id >= 0 && (gb_id >> 8) == sc){
      const int r = qg*16 + gb_r;
      const int sl = gb_id & 255;
      pvb = (float)Pc[r*256 + ((((sl >> 3) ^ (r & 7)) << 3) | (sl & 7))];
    }
    __builtin_amdgcn_s_barrier();   // readers of Pc + V slot (sc&1) done
  }
  const f32x4 o = (oo0 + oo1) + (oo2 + oo3);

  // ---- deferred gather stores ----
  gpart[((size_t)bh*T_ + t0 + qg*16 + ga_r)*KN + ga_kk] = pva/lr_a*0.125f;
  if (gb_id >= 0)
    gpart[((size_t)bh*T_ + t0 + qg*16 + gb_r)*KN + gb_kk] = pvb/lr_b*0.125f;

#pragma unroll
  for (int j = 0; j < 4; ++j){
    const float lr = __shfl(lrq, l4*4 + j);
    const int t = t0 + qg*16 + l4*4 + j;
    X2[((size_t)(bi*T_ + t))*640 + h*HD_ + ws*16 + l16] = (f16)(o[j]/lr);
  }
}

// ---------------- edge: weighted neighbor-embedding mean -------------------
__global__ __launch_bounds__(128) void edge_kernel(
    const float* __restrict__ gpart, const float* __restrict__ E, f16* __restrict__ X2)
{
  __shared__ float gl[KN];
  __shared__ float ginv;
  const int bt = blockIdx.x;          // b*T + t
  const int bi = bt >> 10, tt = bt & 1023;
  const int t = threadIdx.x;
  if (t < KN){
    float s = 0.f;
#pragma unroll
    for (int hh = 0; hh < H_; ++hh)
      s += gpart[((size_t)(bi*H_ + hh)*T_ + tt)*KN + t];
    gl[t] = s;
  }
  __syncthreads();
  if (t == 0){
    float s = 0.f;
#pragma unroll
    for (int i = 0; i < KN; ++i) s += gl[i];
    ginv = 1.0f/(s + 1e-6f);
  }
  __syncthreads();
  float acc = 0.f;
  const float* Ep = E + (size_t)bt*KN*ED_ + t;
#pragma unroll 5
  for (int kk = 0; kk < KN; ++kk) acc += gl[kk]*Ep[(size_t)kk*ED_];
  X2[(size_t)bt*640 + 512 + t] = (f16)(acc*ginv);
}

// ---------------- LayerNorm helpers ----------------------------------------
__device__ __forceinline__ float block_sum(float v, float* sbuf){
  for (int o = 32; o; o >>= 1) v += __shfl_down(v, o);
  __syncthreads();
  if ((threadIdx.x & 63) == 0) sbuf[threadIdx.x >> 6] = v;
  __syncthreads();
  return sbuf[0]+sbuf[1]+sbuf[2]+sbuf[3];
}

__global__ __launch_bounds__(256) void ln1_kernel(
    const float* __restrict__ hV, const f16* __restrict__ hraw,
    const float* __restrict__ gn, const float* __restrict__ bn,
    f16* __restrict__ hh)
{
  __shared__ float sbuf[4];
  const int r = blockIdx.x, t = threadIdx.x;
  const size_t base = (size_t)r*D_;
  const size_t MD = (size_t)M_*D_;
  float x0 = hV[base+t]     + (float)hraw[base+t]     + (float)hraw[MD+base+t];
  float x1 = hV[base+t+256] + (float)hraw[base+t+256] + (float)hraw[MD+base+t+256];
  float s = block_sum(x0+x1, sbuf);
  const float mean = s*(1.f/512.f);
  float d0 = x0-mean, d1 = x1-mean;
  float vs = block_sum(d0*d0+d1*d1, sbuf);
  const float rstd = rsqrtf(vs*(1.f/512.f) + 1e-5f);
  hh[base+t]     = (f16)(d0*rstd*gn[t]     + bn[t]);
  hh[base+t+256] = (f16)(d1*rstd*gn[t+256] + bn[t+256]);
}

__global__ __launch_bounds__(256) void final_kernel(
    const f16* __restrict__ hh, const f16* __restrict__ ffr,
    const float* __restrict__ gf, const float* __restrict__ bfv,
    const float* __restrict__ g2, const float* __restrict__ b2,
    float* __restrict__ out)
{
  __shared__ float sbuf[4];
  const int r = blockIdx.x, t = threadIdx.x;
  const size_t base = (size_t)r*D_;
  const size_t MD = (size_t)M_*D_;
  const float h0 = (float)hh[base+t], h1 = (float)hh[base+t+256];
  float x0 = h0 + (float)ffr[base+t]     + (float)ffr[MD+base+t];
  float x1 = h1 + (float)ffr[base+t+256] + (float)ffr[MD+base+t+256];
  float s = block_sum(x0+x1, sbuf);
  float mean = s*(1.f/512.f);
  float d0 = x0-mean, d1 = x1-mean;
  float vs = block_sum(d0*d0+d1*d1, sbuf);
  float rstd = rsqrtf(vs*(1.f/512.f) + 1e-6f);
  const float dh0 = d0*rstd*gf[t]     + bfv[t];
  const float dh1 = d1*rstd*gf[t+256] + bfv[t+256];
  const float y0 = h0 + dh0, y1 = h1 + dh1;
  s = block_sum(y0+y1, sbuf);
  mean = s*(1.f/512.f);
  d0 = y0-mean; d1 = y1-mean;
  vs = block_sum(d0*d0+d1*d1, sbuf);
  rstd = rsqrtf(vs*(1.f/512.f) + 1e-5f);
  out[base+t]     = d0*rstd*g2[t]     + b2[t];
  out[base+t+256] = d1*rstd*g2[t+256] + b2[t+256];
}

// ---------------------------------------------------------------------------
extern "C" void kernel_launch(void* const* d_in, const int* in_sizes, int n_in,
                              void* d_out, int out_size, void* d_ws, size_t ws_size,
                              hipStream_t stream)
{
  (void)in_sizes; (void)n_in; (void)out_size;
  const float* h_V  = (const float*)d_in[0];
  const float* kin  = (const float*)d_in[1];
  const float* vin  = (const float*)d_in[2];
  const float* E    = (const float*)d_in[3];
  const float* bias = (const float*)d_in[4];
  const float* Wq   = (const float*)d_in[5];
  const float* bq   = (const float*)d_in[6];
  const float* Wk   = (const float*)d_in[7];
  const float* bk   = (const float*)d_in[8];
  const float* Wv   = (const float*)d_in[9];
  const float* bv   = (const float*)d_in[10];
  const float* Wo   = (const float*)d_in[11];
  const float* bo   = (const float*)d_in[12];
  const float* tsc  = (const float*)d_in[13];
  const float* gn   = (const float*)d_in[14];
  const float* bn   = (const float*)d_in[15];
  const float* w1   = (const float*)d_in[16];
  const float* bw1  = (const float*)d_in[17];
  const float* w2   = (const float*)d_in[18];
  const float* bw2  = (const float*)d_in[19];
  const float* gf   = (const float*)d_in[20];
  const float* bfv  = (const float*)d_in[21];
  const float* g2   = (const float*)d_in[22];
  const float* b2   = (const float*)d_in[23];
  const int*   Eidx = (const int*)d_in[24];
  const int*   mask = (const int*)d_in[25];
  float* out = (float*)d_out;

  char* wsb = (char*)d_ws;
  size_t off = 0;
  auto alloc = [&](size_t bytes) -> void* {
    void* pp = wsb + off; off += (bytes + 255) & ~(size_t)255; return pp;
  };
  f16* hVb  = (f16*)alloc((size_t)M_*D_*2);
  f16* kbI  = (f16*)alloc((size_t)M_*D_*2);
  f16* vbI  = (f16*)alloc((size_t)M_*D_*2);
  f16* Wqb  = (f16*)alloc((size_t)D_*D_*2);
  f16* Wkb  = (f16*)alloc((size_t)D_*D_*2);
  f16* Wvb  = (f16*)alloc((size_t)D_*D_*2);
  f16* Wob  = (f16*)alloc((size_t)D_*(D_+ED_)*2);
  f16* w1b  = (f16*)alloc((size_t)DFF_*D_*2);
  f16* w2b  = (f16*)alloc((size_t)D_*DFF_*2);
  f16* qb   = (f16*)alloc((size_t)M_*D_*2);
  f16* kb   = (f16*)alloc((size_t)M_*D_*2);
  f16* vT   = (f16*)alloc((size_t)M_*D_*2);
  f16* biasT= (f16*)alloc((size_t)B_*T_*T_*2);
  f16* X2   = (f16*)alloc((size_t)M_*640*2);
  float* gpart = (float*)alloc((size_t)BH_*T_*KN*4);
  f16* hraw = (f16*)alloc((size_t)2*M_*D_*2);  // split-K partials (reused as ffraw)
  f16* hh   = (f16*)alloc((size_t)M_*D_*2);
  f16* ff1  = (f16*)alloc((size_t)M_*DFF_*2);
  if (ws_size < off) return;  // scratch insufficient -> loud validation failure
  f16* ffraw = hraw;

  // 1) fused prep: 9x fp32->f16 convert + fragment-tiled biasT (one launch)
  {
    CvtJobs J;
    const float* srcs[9] = {h_V, kin, vin, Wq, Wk, Wv, Wo, w1, w2};
    f16* dsts[9] = {hVb, kbI, vbI, Wqb, Wkb, Wvb, Wob, w1b, w2b};
    const int n4s[9] = {M_*D_/4, M_*D_/4, M_*D_/4, D_*D_/4, D_*D_/4, D_*D_/4,
                        D_*(D_+ED_)/4, DFF_*D_/4, D_*DFF_/4};
    int cum = 0;
    for (int i = 0; i < 9; ++i){
      J.s[i] = srcs[i]; J.d[i] = dsts[i]; J.start[i] = cum;
      cum += n4s[i]/256;
    }
    J.start[9] = cum;
    prep_kernel<<<cum + 2048,256,0,stream>>>(J, cum, bias, mask, tsc, biasT);
  }

  // 2) batched q/k/v projections, BK=64 pipelined (q pre-scaled; v -> vT)
  qkv_tile<<<384,256,0,stream>>>(hVb, kbI, vbI, Wqb, Wkb, Wvb, bq, bk, bv, tsc, qb, kb, vT);

  // 3) fused attention (QBLK=32, 256-s chunks), 1024 blocks x 512 thr
  attn_fused<<<1024,512,0,stream>>>(qb, kb, vT, biasT, Eidx, X2, gpart);

  // 4) edge embedding (sums 8 per-head partials)
  edge_kernel<<<M_,128,0,stream>>>(gpart, E, X2);

  // 5) out-proj split-K=2 (512 blocks) + residual LN (sums partials)
  gemm_n64<2,2><<<512,256,0,stream>>>(X2, Wob, bo, hraw, D_+ED_, D_, 8);
  ln1_kernel<<<M_,256,0,stream>>>(h_V, hraw, gn, bn, hh);

  // 6) FFN: FF1 gelu f16 (pipelined), FF2 split-K=2 (512 blocks)
  gemm_tile<1><<<512,256,0,stream>>>(hh, w1b, bw1, ff1, D_, DFF_, 16);
  gemm_n64<2,2><<<512,256,0,stream>>>(ff1, w2b, bw2, ffraw, DFF_, D_, 8);

  // 7) final double-LN (sums FF2 partials)
  final_kernel<<<M_,256,0,stream>>>(hh, ffraw, gf, bfv, g2, b2, out);
}

// Round 23
// 145.702 us; speedup vs baseline: 1.0000x; 1.0000x over previous
//
#include <hip/hip_runtime.h>
#include <hip/hip_fp16.h>
#include <math.h>

#define B_ 4
#define T_ 1024
#define D_ 512
#define H_ 8
#define HD_ 64
#define KN 30
#define ED_ 128
#define DFF_ 2048
#define M_ 4096   // B*T
#define BH_ 32

typedef _Float16 f16;
typedef __attribute__((ext_vector_type(8))) _Float16 f16x8;
typedef __attribute__((ext_vector_type(4))) _Float16 f16x4;
typedef __attribute__((ext_vector_type(4))) float f32x4;

#define MFMA16 __builtin_amdgcn_mfma_f32_16x16x32_f16
#define LOG2E 1.44269504088896f

__device__ __forceinline__ f16x8 ld8(const f16* p){ return *reinterpret_cast<const f16x8*>(p); }

__device__ __forceinline__ void gld16(const void* g, void* l){
  __builtin_amdgcn_global_load_lds((const __attribute__((address_space(1))) void*)g,
                                   (__attribute__((address_space(3))) void*)l, 16, 0, 0);
}

// ---------------- fused prep: 9x fp32->f16 convert + bias prep --------------
struct CvtJobs {
  const float* s[9];
  f16* d[9];
  int start[10];   // cumulative block starts; each block = 256 float4s
};

// blocks [0, cvtBlocks): convert; blocks [cvtBlocks, +2048): biasprep.
// biasT layout (QBLK=32): for (bi,tb,c,ws,qg,l16,l4), 8 f16 at u*8 =
// [step0 j0..3 | step1 j0..3] of scaled bias[t=tb*32+qg*16+l16]
// [s=c*128+ws*32+step*16+l4*4+j].
__global__ __launch_bounds__(256) void prep_kernel(
    CvtJobs J, int cvtBlocks,
    const float* __restrict__ bias, const int* __restrict__ mask,
    const float* __restrict__ tsc, f16* __restrict__ biasT)
{
  if (blockIdx.x < cvtBlocks){
    const int blk = blockIdx.x;
    int j = 0;
    while (j < 8 && blk >= J.start[j+1]) ++j;
    const int i = (blk - J.start[j])*256 + threadIdx.x;
    float4 v = reinterpret_cast<const float4*>(J.s[j])[i];
    union { f16 h[4]; ushort4 u; } o;
    o.h[0]=(f16)v.x; o.h[1]=(f16)v.y; o.h[2]=(f16)v.z; o.h[3]=(f16)v.w;
    reinterpret_cast<ushort4*>(J.d[j])[i] = o.u;
    return;
  }
  const int u = (blockIdx.x - cvtBlocks)*256 + threadIdx.x;   // 524288 threads
  const int l4 = u & 3, l16 = (u >> 2) & 15, qg = (u >> 6) & 1;
  const int ws = (u >> 7) & 3, c = (u >> 9) & 7, tb = (u >> 12) & 31, bi = u >> 17;
  const float s = exp2f(-2.0f*tanhf(tsc[0]))*LOG2E;  // log2e / 4^tanh(t)
  const int t  = tb*32 + qg*16 + l16;
  const int s0 = c*128 + ws*32 + l4*4;
  const float* bp = bias + ((size_t)bi*T_ + t)*T_ + s0;
  const int*   mp = mask + bi*T_ + s0;
  union { f16 h[8]; f16x8 v8; } o;
#pragma unroll
  for (int st = 0; st < 2; ++st){
    float4 v = *reinterpret_cast<const float4*>(bp + st*16);
    int4  mm = *reinterpret_cast<const int4*>(mp + st*16);
    float x[4] = {v.x,v.y,v.z,v.w};
    int  m4[4] = {mm.x,mm.y,mm.z,mm.w};
#pragma unroll
    for (int j = 0; j < 4; ++j){
      float tv = (x[j] + (m4[j] ? 0.f : -60000.f))*s;
      o.h[st*4 + j] = (f16)fmaxf(tv, -60000.f);
    }
  }
  *reinterpret_cast<f16x8*>(biasT + (size_t)u*8) = o.v8;
}

// =============== staged MFMA GEMM: C = X @ W.T, BK=64, XOR-swizzled =========
// Ping-pong LDS + counted vmcnt(8). EPI 1: gelu; EPI 2: raw f16.
template<int EPI>
__global__ __launch_bounds__(256,2) void gemm_tile(
    const f16* __restrict__ X, const f16* __restrict__ W,
    const float* __restrict__ bias, void* __restrict__ outp,
    int Kd, int ldo, int nbN)
{
  __shared__ f16 As[2*8192];   // 2 x [128][64]
  __shared__ f16 Bs[2*8192];
  const int nwg = gridDim.x;
  const int bid = blockIdx.x;
  const int swz = (bid & 7)*(nwg >> 3) + (bid >> 3);
  const int mb = swz / nbN, nb = swz - mb*nbN;
  const int rb = mb*128, cb = nb*128;
  const int tid = threadIdx.x;
  const int w = tid >> 6, lane = tid & 63;
  const int l16 = lane & 15, l4 = lane >> 4;
  const int wr = w >> 1, wc = w & 1;
  const int key = l16 & 7;

  auto stage = [&](int ph, int slot){
#pragma unroll
    for (int i = 0; i < 4; ++i){
      const int cidx = i*256 + w*64 + lane;
      const int r = cidx >> 3, p = cidx & 7;
      gld16(X + (size_t)(rb + r)*Kd + ph*64 + ((p ^ (r & 7)) << 3),
            &As[slot*8192 + (i*256 + w*64)*8]);
      gld16(W + (size_t)(cb + r)*Kd + ph*64 + ((p ^ (r & 7)) << 3),
            &Bs[slot*8192 + (i*256 + w*64)*8]);
    }
  };

  f32x4 acc[4][4];
#pragma unroll
  for (int m = 0; m < 4; ++m)
#pragma unroll
    for (int n = 0; n < 4; ++n) acc[m][n] = (f32x4){0.f,0.f,0.f,0.f};

  const int nPh = Kd >> 6;
  stage(0, 0);
  for (int ph = 0; ph < nPh; ++ph){
    if (ph < nPh-1) stage(ph+1, (ph+1)&1);
    if (ph < nPh-1) asm volatile("s_waitcnt vmcnt(8)" ::: "memory");
    else            asm volatile("s_waitcnt vmcnt(0)" ::: "memory");
    __builtin_amdgcn_sched_barrier(0);
    __builtin_amdgcn_s_barrier();
    __builtin_amdgcn_sched_barrier(0);
    const int base = (ph&1)*8192;
#pragma unroll
    for (int kk = 0; kk < 2; ++kk){
      f16x8 a[4], b[4];
#pragma unroll
      for (int m = 0; m < 4; ++m)
        a[m] = ld8(&As[base + (wr*64 + m*16 + l16)*64 + (((kk*4 + l4) ^ key) << 3)]);
#pragma unroll
      for (int n = 0; n < 4; ++n)
        b[n] = ld8(&Bs[base + (wc*64 + n*16 + l16)*64 + (((kk*4 + l4) ^ key) << 3)]);
#pragma unroll
      for (int m = 0; m < 4; ++m)
#pragma unroll
        for (int n = 0; n < 4; ++n)
          acc[m][n] = MFMA16(a[m], b[n], acc[m][n], 0,0,0);
    }
    __builtin_amdgcn_s_barrier();   // readers of slot (ph&1) done
  }

#pragma unroll
  for (int n = 0; n < 4; ++n){
    const int col = cb + wc*64 + n*16 + l16;
    const float bv = bias[col];
#pragma unroll
    for (int m = 0; m < 4; ++m){
#pragma unroll
      for (int j = 0; j < 4; ++j){
        const int row = rb + wr*64 + m*16 + l4*4 + j;
        float v = acc[m][n][j] + bv;
        if (EPI == 1) v = 0.5f*v*(1.0f + erff(v*0.70710678118654752f));
        ((f16*)outp)[(size_t)row*ldo + col] = (f16)v;
      }
    }
  }
}

// =============== 128x64-tile GEMM, BK=64, pipelined, split-K ================
// KS slices: slice ks covers K range [ks*Kd/KS, +Kd/KS); writes partial f16
// at outp + ks*M*ldo (bias folded into slice 0 only). Consumer sums slices.
template<int EPI, int KS>
__global__ __launch_bounds__(256,3) void gemm_n64(
    const f16* __restrict__ X, const f16* __restrict__ W,
    const float* __restrict__ bias, void* __restrict__ outp,
    int Kd, int ldo, int nbN)
{
  __shared__ f16 As[2*8192];   // 2 x [128][64]
  __shared__ f16 Bs[2*4096];   // 2 x [64][64]
  const int nwg = gridDim.x;
  const int bid = blockIdx.x;
  const int swz = (bid & 7)*(nwg >> 3) + (bid >> 3);
  const int per = nwg / KS;
  const int ks = swz / per;
  const int r2 = swz - ks*per;
  const int mb = r2 / nbN, nb = r2 - mb*nbN;
  const int rb = mb*128, cb = nb*64;
  const int kOff = ks*(Kd/KS);
  const int tid = threadIdx.x;
  const int w = tid >> 6, lane = tid & 63;
  const int l16 = lane & 15, l4 = lane >> 4;
  const int wr = w >> 1, wc = w & 1;
  const int key = l16 & 7;

  auto stage = [&](int ph, int slot){
#pragma unroll
    for (int i = 0; i < 4; ++i){
      const int cidx = i*256 + w*64 + lane;
      const int r = cidx >> 3, p = cidx & 7;
      gld16(X + (size_t)(rb + r)*Kd + kOff + ph*64 + ((p ^ (r & 7)) << 3),
            &As[slot*8192 + (i*256 + w*64)*8]);
    }
#pragma unroll
    for (int i = 0; i < 2; ++i){
      const int cidx = i*256 + w*64 + lane;
      const int r = cidx >> 3, p = cidx & 7;
      gld16(W + (size_t)(cb + r)*Kd + kOff + ph*64 + ((p ^ (r & 7)) << 3),
            &Bs[slot*4096 + (i*256 + w*64)*8]);
    }
  };

  f32x4 acc[4][2];
#pragma unroll
  for (int m = 0; m < 4; ++m)
#pragma unroll
    for (int n = 0; n < 2; ++n) acc[m][n] = (f32x4){0.f,0.f,0.f,0.f};

  const int nPh = (Kd/KS) >> 6;
  stage(0, 0);
  for (int ph = 0; ph < nPh; ++ph){
    if (ph < nPh-1) stage(ph+1, (ph+1)&1);
    if (ph < nPh-1) asm volatile("s_waitcnt vmcnt(6)" ::: "memory");
    else            asm volatile("s_waitcnt vmcnt(0)" ::: "memory");
    __builtin_amdgcn_sched_barrier(0);
    __builtin_amdgcn_s_barrier();
    __builtin_amdgcn_sched_barrier(0);
    const int baseA = (ph&1)*8192, baseB = (ph&1)*4096;
#pragma unroll
    for (int kk = 0; kk < 2; ++kk){
      f16x8 a[4], b[2];
#pragma unroll
      for (int m = 0; m < 4; ++m)
        a[m] = ld8(&As[baseA + (wr*64 + m*16 + l16)*64 + (((kk*4 + l4) ^ key) << 3)]);
#pragma unroll
      for (int n = 0; n < 2; ++n)
        b[n] = ld8(&Bs[baseB + (wc*32 + n*16 + l16)*64 + (((kk*4 + l4) ^ key) << 3)]);
#pragma unroll
      for (int m = 0; m < 4; ++m)
#pragma unroll
        for (int n = 0; n < 2; ++n)
          acc[m][n] = MFMA16(a[m], b[n], acc[m][n], 0,0,0);
    }
    __builtin_amdgcn_s_barrier();
  }

#pragma unroll
  for (int n = 0; n < 2; ++n){
    const int col = cb + wc*32 + n*16 + l16;
    const float bv = (ks == 0) ? bias[col] : 0.f;
#pragma unroll
    for (int m = 0; m < 4; ++m){
#pragma unroll
      for (int j = 0; j < 4; ++j){
        const int row = rb + wr*64 + m*16 + l4*4 + j;
        float v = acc[m][n][j] + bv;
        if (EPI == 1) v = 0.5f*v*(1.0f + erff(v*0.70710678118654752f));
        ((f16*)outp)[(size_t)ks*M_*ldo + (size_t)row*ldo + col] = (f16)v;
      }
    }
  }
}

// =============== batched QKV projection, BK=64, pipelined ===================
// grid 384: gemm g in {q,k,v}, 128 blocks each. q folds 0.125*rtemp*log2e;
// v written pre-transposed vT[(b*H+h)*HD+dl][t].
__global__ __launch_bounds__(256,2) void qkv_tile(
    const f16* __restrict__ hV, const f16* __restrict__ kI, const f16* __restrict__ vI,
    const f16* __restrict__ Wq, const f16* __restrict__ Wk, const f16* __restrict__ Wv,
    const float* __restrict__ bq, const float* __restrict__ bk, const float* __restrict__ bv,
    const float* __restrict__ tsc,
    f16* __restrict__ qo, f16* __restrict__ ko, f16* __restrict__ vT)
{
  __shared__ f16 As[2*8192];
  __shared__ f16 Bs[2*8192];
  const int bid = blockIdx.x;
  const int swz = (bid & 7)*48 + (bid >> 3);
  const int g = swz >> 7;
  const int r = swz & 127;
  const int mb = r >> 2, nb = r & 3;
  const f16* X  = (g == 0) ? hV : ((g == 1) ? kI : vI);
  const f16* W  = (g == 0) ? Wq : ((g == 1) ? Wk : Wv);
  const float* bias = (g == 0) ? bq : ((g == 1) ? bk : bv);
  const int rb = mb*128, cb = nb*128;
  const int tid = threadIdx.x;
  const int w = tid >> 6, lane = tid & 63;
  const int l16 = lane & 15, l4 = lane >> 4;
  const int wr = w >> 1, wc = w & 1;
  const int key = l16 & 7;

  auto stage = [&](int ph, int slot){
#pragma unroll
    for (int i = 0; i < 4; ++i){
      const int cidx = i*256 + w*64 + lane;
      const int rr = cidx >> 3, p = cidx & 7;
      gld16(X + (size_t)(rb + rr)*D_ + ph*64 + ((p ^ (rr & 7)) << 3),
            &As[slot*8192 + (i*256 + w*64)*8]);
      gld16(W + (size_t)(cb + rr)*D_ + ph*64 + ((p ^ (rr & 7)) << 3),
            &Bs[slot*8192 + (i*256 + w*64)*8]);
    }
  };

  f32x4 acc[4][4];
#pragma unroll
  for (int m = 0; m < 4; ++m)
#pragma unroll
    for (int n = 0; n < 4; ++n) acc[m][n] = (f32x4){0.f,0.f,0.f,0.f};

  stage(0, 0);
#pragma unroll
  for (int ph = 0; ph < 8; ++ph){
    if (ph < 7) stage(ph+1, (ph+1)&1);
    if (ph < 7) asm volatile("s_waitcnt vmcnt(8)" ::: "memory");
    else        asm volatile("s_waitcnt vmcnt(0)" ::: "memory");
    __builtin_amdgcn_sched_barrier(0);
    __builtin_amdgcn_s_barrier();
    __builtin_amdgcn_sched_barrier(0);
    const int base = (ph&1)*8192;
#pragma unroll
    for (int kk = 0; kk < 2; ++kk){
      f16x8 a[4], b[4];
#pragma unroll
      for (int m = 0; m < 4; ++m)
        a[m] = ld8(&As[base + (wr*64 + m*16 + l16)*64 + (((kk*4 + l4) ^ key) << 3)]);
#pragma unroll
      for (int n = 0; n < 4; ++n)
        b[n] = ld8(&Bs[base + (wc*64 + n*16 + l16)*64 + (((kk*4 + l4) ^ key) << 3)]);
#pragma unroll
      for (int m = 0; m < 4; ++m)
#pragma unroll
        for (int n = 0; n < 4; ++n)
          acc[m][n] = MFMA16(a[m], b[n], acc[m][n], 0,0,0);
    }
    __builtin_amdgcn_s_barrier();
  }

  const float qs = exp2f(-2.0f*tanhf(tsc[0]))*LOG2E*0.125f;
  const float scale = (g == 0) ? qs : 1.0f;
  f16* out = (g == 0) ? qo : ko;
#pragma unroll
  for (int n = 0; n < 4; ++n){
    const int col = cb + wc*64 + n*16 + l16;
    const float bv = bias[col];
#pragma unroll
    for (int m = 0; m < 4; ++m){
#pragma unroll
      for (int j = 0; j < 4; ++j){
        const int row = rb + wr*64 + m*16 + l4*4 + j;
        const float v = (acc[m][n][j] + bv)*scale;
        if (g < 2){
          out[(size_t)row*D_ + col] = (f16)v;
        } else {
          const int b = row >> 10, t = row & (T_-1);
          const int h = col >> 6,  dl = col & (HD_-1);
          vT[(((size_t)b*H_ + h)*HD_ + dl)*T_ + t] = (f16)v;
        }
      }
    }
  }
}

// =============== fused attention (QBLK=32, 3-slot ring, depth-2) ============
// 8 waves: qg=w>>2 owns q-group, ws=w&3 owns s-subrange / d-cols.
// K/V staged through a 3-slot LDS ring: chunks c+1,c+2 in flight across each
// barrier (s_waitcnt vmcnt(4) mid-loop; 2 gld16/lane per stage). Bias
// fragments preloaded to registers; gather captured in regs, stored after.
__global__ __launch_bounds__(512,4) void attn_fused(
    const f16* __restrict__ q, const f16* __restrict__ k, const f16* __restrict__ vT,
    const f16* __restrict__ biasT, const int* __restrict__ eidx,
    f16* __restrict__ X2, float* __restrict__ gpart)
{
  __shared__ f16 Sb[3*8192];      // 48 KB: K/V chunk ring
  __shared__ f16 Pc[32*128];      // 8 KB: P chunk [32 q][128 s]
  const int bid = blockIdx.x;
  const int swz = (bid & 7)*128 + (bid >> 3);   // XCD-contiguous
  const int bh = swz >> 5, tb = swz & 31;
  const int bi = bh >> 3, h = bh & 7;
  const int t0 = tb*32;
  const int tid = threadIdx.x, w = tid >> 6, lane = tid & 63;
  const int qg = w >> 2, ws = w & 3;
  const int l16 = lane & 15, l4 = lane >> 4;
  const int key = l16 & 7;

  // ---- Q fragments ----
  const f16* qp = q + (size_t)(bi*T_ + t0 + qg*16 + l16)*D_ + h*HD_ + l4*8;
  const f16x8 q0 = ld8(qp), q1 = ld8(qp + 32);
  // ---- bias fragments: one f16x8 per chunk, preloaded ----
  const f16* bb = biasT + (size_t)(bi*32 + tb)*32768 + ws*1024 + qg*512 + l16*32 + l4*8;
  f16x8 bfr[8];
#pragma unroll
  for (int c = 0; c < 8; ++c) bfr[c] = ld8(bb + c*4096);
  // ---- gather tuples: each tid handles items of its own qg half ----
  const int tl = tid & 255;
  int ga_r, ga_kk, ga_id, gb_r = 0, gb_kk = 0, gb_id = -1;
  ga_r = tl/KN; ga_kk = tl - ga_r*KN;
  ga_id = eidx[((size_t)(bi*T_ + t0 + qg*16 + ga_r))*KN + ga_kk];
  if (tl + 256 < 16*KN){
    gb_r = (tl+256)/KN; gb_kk = (tl+256) - gb_r*KN;
    gb_id = eidx[((size_t)(bi*T_ + t0 + qg*16 + gb_r))*KN + gb_kk];
  }

  const f16* kg = k + (size_t)(bi*T_)*D_ + h*HD_;
  const f16* vg = vT + (size_t)bh*HD_*T_;

  auto stageK = [&](int c, int slot){
#pragma unroll
    for (int i = 0; i < 2; ++i){
      const int cidx = i*512 + w*64 + lane;
      const int r = cidx >> 3, p = cidx & 7;
      gld16(kg + (size_t)(c*128 + r)*D_ + ((p ^ (r & 7)) << 3),
            &Sb[slot*8192 + (i*512 + w*64)*8]);
    }
  };
  auto stageV = [&](int sc, int slot){
#pragma unroll
    for (int i = 0; i < 2; ++i){
      const int cidx = i*512 + w*64 + lane;
      const int r = cidx >> 4, p = cidx & 15;
      gld16(vg + (size_t)r*T_ + sc*128 + ((p ^ (r & 7)) << 3),
            &Sb[slot*8192 + (i*512 + w*64)*8]);
    }
  };

  // ---- QK^T: 8 chunks of 128 s; 3-slot ring, 2 chunks in flight ----
  f32x4 acc[16];
  stageK(0, 0);
  stageK(1, 1);
#pragma unroll
  for (int c = 0; c < 8; ++c){
    if (c < 6) stageK(c+2, (c+2)%3);
    if (c < 6)      asm volatile("s_waitcnt vmcnt(4)" ::: "memory");
    else if (c == 6) asm volatile("s_waitcnt vmcnt(2)" ::: "memory");
    else             asm volatile("s_waitcnt vmcnt(0)" ::: "memory");
    __builtin_amdgcn_sched_barrier(0);
    __builtin_amdgcn_s_barrier();
    __builtin_amdgcn_sched_barrier(0);
    const int base = (c%3)*8192;
#pragma unroll
    for (int step = 0; step < 2; ++step){
      const int rr = ws*32 + step*16 + l16;
      f32x4 a = {0.f,0.f,0.f,0.f};
      a = MFMA16(ld8(&Sb[base + rr*64 + ((l4 ^ key) << 3)]),       q0, a, 0,0,0);
      a = MFMA16(ld8(&Sb[base + rr*64 + (((4 + l4) ^ key) << 3)]), q1, a, 0,0,0);
#pragma unroll
      for (int j = 0; j < 4; ++j) a[j] += (float)bfr[c][step*4 + j];
      acc[c*2 + step] = a;
    }
    __builtin_amdgcn_s_barrier();   // readers of slot (c%3) done
  }

  // ---- softmax (stats overlay on idle Sb; sums redistributed via shfl) ----
  float* redf = (float*)Sb;         // [0..127]=max, [128..255]=sum
  float m = -3.4e38f;
#pragma unroll
  for (int c = 0; c < 16; ++c)
#pragma unroll
    for (int j = 0; j < 4; ++j) m = fmaxf(m, acc[c][j]);
  m = fmaxf(m, __shfl_xor(m, 16));
  m = fmaxf(m, __shfl_xor(m, 32));
  if (lane < 16) redf[(qg*4 + ws)*16 + lane] = m;
  __syncthreads();
  m = fmaxf(fmaxf(redf[(qg*4+0)*16 + l16], redf[(qg*4+1)*16 + l16]),
            fmaxf(redf[(qg*4+2)*16 + l16], redf[(qg*4+3)*16 + l16]));
  float l = 0.f;
#pragma unroll
  for (int c = 0; c < 16; ++c)
#pragma unroll
    for (int j = 0; j < 4; ++j){
      const float e = exp2f(acc[c][j] - m);
      l += e;
      acc[c][j] = e;                // acc now holds unnormalized P
    }
  l += __shfl_xor(l, 16);
  l += __shfl_xor(l, 32);
  if (lane < 16) redf[128 + (qg*4 + ws)*16 + lane] = l;
  __syncthreads();
  const float lrq = redf[128 + (qg*4+0)*16 + l16] + redf[128 + (qg*4+1)*16 + l16]
                  + redf[128 + (qg*4+2)*16 + l16] + redf[128 + (qg*4+3)*16 + l16];
  __syncthreads();                  // all lrq reads done before V staging clobbers
  const float lr_a = __shfl(lrq, ga_r);
  const float lr_b = __shfl(lrq, gb_r);

  // ---- PV: 8 chunks; 3-slot ring, 2 chunks in flight; gather -> regs ----
  f32x4 oo0 = {0.f,0.f,0.f,0.f}, oo1 = oo0, oo2 = oo0, oo3 = oo0;
  float pva = 0.f, pvb = 0.f;
  stageV(0, 0);
  stageV(1, 1);
#pragma unroll
  for (int sc = 0; sc < 8; ++sc){
    // write own P slice for chunk sc (Pc free: prior readers barrier'd)
#pragma unroll
    for (int step = 0; step < 2; ++step){
      const int slb = ws*32 + step*16 + l4*4;
      f16x4 pp;
#pragma unroll
      for (int j = 0; j < 4; ++j) pp[j] = (f16)acc[sc*2 + step][j];
      *reinterpret_cast<f16x4*>(
          &Pc[(qg*16 + l16)*128 + (((slb >> 3) ^ key) << 3) + (slb & 7)]) = pp;
    }
    if (sc < 6) stageV(sc+2, (sc+2)%3);
    if (sc < 6)      asm volatile("s_waitcnt vmcnt(4) lgkmcnt(0)" ::: "memory");
    else if (sc == 6) asm volatile("s_waitcnt vmcnt(2) lgkmcnt(0)" ::: "memory");
    else              asm volatile("s_waitcnt vmcnt(0) lgkmcnt(0)" ::: "memory");
    __builtin_amdgcn_sched_barrier(0);
    __builtin_amdgcn_s_barrier();
    __builtin_amdgcn_sched_barrier(0);
    const int base = (sc%3)*8192;
    const int vrow = (ws*16 + l16)*128;
#pragma unroll
    for (int grp = 0; grp < 4; ++grp){
      const int ch = (grp*4 + l4) ^ key;
      const f16x8 pa = ld8(&Pc[(qg*16 + l16)*128 + (ch << 3)]);
      const f16x8 vb = ld8(&Sb[base + vrow + (ch << 3)]);
      if (grp == 0)      oo0 = MFMA16(pa, vb, oo0, 0,0,0);
      else if (grp == 1) oo1 = MFMA16(pa, vb, oo1, 0,0,0);
      else if (grp == 2) oo2 = MFMA16(pa, vb, oo2, 0,0,0);
      else               oo3 = MFMA16(pa, vb, oo3, 0,0,0);
    }
    // edge gather capture (no VMEM stores inside the loop)
    if ((ga_id >> 7) == sc){
      const int r = qg*16 + ga_r;
      const int sl = ga_id & 127;
      pva = (float)Pc[r*128 + ((((sl >> 3) ^ (r & 7)) << 3) | (sl & 7))];
    }
    if (gb_id >= 0 && (gb_id >> 7) == sc){
      const int r = qg*16 + gb_r;
      const int sl = gb_id & 127;
      pvb = (float)Pc[r*128 + ((((sl >> 3) ^ (r & 7)) << 3) | (sl & 7))];
    }
    __builtin_amdgcn_s_barrier();   // readers of Pc + V slot (sc%3) done
  }
  const f32x4 o = (oo0 + oo1) + (oo2 + oo3);

  // ---- deferred gather stores ----
  gpart[((size_t)bh*T_ + t0 + qg*16 + ga_r)*KN + ga_kk] = pva/lr_a*0.125f;
  if (gb_id >= 0)
    gpart[((size_t)bh*T_ + t0 + qg*16 + gb_r)*KN + gb_kk] = pvb/lr_b*0.125f;

#pragma unroll
  for (int j = 0; j < 4; ++j){
    const float lr = __shfl(lrq, l4*4 + j);
    const int t = t0 + qg*16 + l4*4 + j;
    X2[((size_t)(bi*T_ + t))*640 + h*HD_ + ws*16 + l16] = (f16)(o[j]/lr);
  }
}

// ---------------- edge: weighted neighbor-embedding mean -------------------
// g[b,t,kk] = sum_h gpart[(b*H+h), t, kk]
__global__ __launch_bounds__(128) void edge_kernel(
    const float* __restrict__ gpart, const float* __restrict__ E, f16* __restrict__ X2)
{
  __shared__ float gl[KN];
  __shared__ float ginv;
  const int bt = blockIdx.x;          // b*T + t
  const int bi = bt >> 10, tt = bt & 1023;
  const int t = threadIdx.x;
  if (t < KN){
    float s = 0.f;
#pragma unroll
    for (int hh = 0; hh < H_; ++hh)
      s += gpart[((size_t)(bi*H_ + hh)*T_ + tt)*KN + t];
    gl[t] = s;
  }
  __syncthreads();
  if (t == 0){
    float s = 0.f;
#pragma unroll
    for (int i = 0; i < KN; ++i) s += gl[i];
    ginv = 1.0f/(s + 1e-6f);
  }
  __syncthreads();
  float acc = 0.f;
  const float* Ep = E + (size_t)bt*KN*ED_ + t;
#pragma unroll 5
  for (int kk = 0; kk < KN; ++kk) acc += gl[kk]*Ep[(size_t)kk*ED_];
  X2[(size_t)bt*640 + 512 + t] = (f16)(acc*ginv);
}

// ---------------- LayerNorm helpers ----------------------------------------
__device__ __forceinline__ float block_sum(float v, float* sbuf){
  for (int o = 32; o; o >>= 1) v += __shfl_down(v, o);
  __syncthreads();
  if ((threadIdx.x & 63) == 0) sbuf[threadIdx.x >> 6] = v;
  __syncthreads();
  return sbuf[0]+sbuf[1]+sbuf[2]+sbuf[3];
}

__global__ __launch_bounds__(256) void ln1_kernel(
    const float* __restrict__ hV, const f16* __restrict__ hraw,
    const float* __restrict__ gn, const float* __restrict__ bn,
    f16* __restrict__ hh)
{
  __shared__ float sbuf[4];
  const int r = blockIdx.x, t = threadIdx.x;
  const size_t base = (size_t)r*D_;
  const size_t MD = (size_t)M_*D_;
  float x0 = hV[base+t]     + (float)hraw[base+t]     + (float)hraw[MD+base+t];
  float x1 = hV[base+t+256] + (float)hraw[base+t+256] + (float)hraw[MD+base+t+256];
  float s = block_sum(x0+x1, sbuf);
  const float mean = s*(1.f/512.f);
  float d0 = x0-mean, d1 = x1-mean;
  float vs = block_sum(d0*d0+d1*d1, sbuf);
  const float rstd = rsqrtf(vs*(1.f/512.f) + 1e-5f);
  hh[base+t]     = (f16)(d0*rstd*gn[t]     + bn[t]);
  hh[base+t+256] = (f16)(d1*rstd*gn[t+256] + bn[t+256]);
}

__global__ __launch_bounds__(256) void final_kernel(
    const f16* __restrict__ hh, const f16* __restrict__ ffr,
    const float* __restrict__ gf, const float* __restrict__ bfv,
    const float* __restrict__ g2, const float* __restrict__ b2,
    float* __restrict__ out)
{
  __shared__ float sbuf[4];
  const int r = blockIdx.x, t = threadIdx.x;
  const size_t base = (size_t)r*D_;
  const size_t MD = (size_t)M_*D_;
  const float h0 = (float)hh[base+t], h1 = (float)hh[base+t+256];
  float x0 = h0 + (float)ffr[base+t]     + (float)ffr[MD+base+t];
  float x1 = h1 + (float)ffr[base+t+256] + (float)ffr[MD+base+t+256];
  float s = block_sum(x0+x1, sbuf);
  float mean = s*(1.f/512.f);
  float d0 = x0-mean, d1 = x1-mean;
  float vs = block_sum(d0*d0+d1*d1, sbuf);
  float rstd = rsqrtf(vs*(1.f/512.f) + 1e-6f);
  const float dh0 = d0*rstd*gf[t]     + bfv[t];
  const float dh1 = d1*rstd*gf[t+256] + bfv[t+256];
  const float y0 = h0 + dh0, y1 = h1 + dh1;
  s = block_sum(y0+y1, sbuf);
  mean = s*(1.f/512.f);
  d0 = y0-mean; d1 = y1-mean;
  vs = block_sum(d0*d0+d1*d1, sbuf);
  rstd = rsqrtf(vs*(1.f/512.f) + 1e-5f);
  out[base+t]     = d0*rstd*g2[t]     + b2[t];
  out[base+t+256] = d1*rstd*g2[t+256] + b2[t+256];
}

// ---------------------------------------------------------------------------
extern "C" void kernel_launch(void* const* d_in, const int* in_sizes, int n_in,
                              void* d_out, int out_size, void* d_ws, size_t ws_size,
                              hipStream_t stream)
{
  (void)in_sizes; (void)n_in; (void)out_size;
  const float* h_V  = (const float*)d_in[0];
  const float* kin  = (const float*)d_in[1];
  const float* vin  = (const float*)d_in[2];
  const float* E    = (const float*)d_in[3];
  const float* bias = (const float*)d_in[4];
  const float* Wq   = (const float*)d_in[5];
  const float* bq   = (const float*)d_in[6];
  const float* Wk   = (const float*)d_in[7];
  const float* bk   = (const float*)d_in[8];
  const float* Wv   = (const float*)d_in[9];
  const float* bv   = (const float*)d_in[10];
  const float* Wo   = (const float*)d_in[11];
  const float* bo   = (const float*)d_in[12];
  const float* tsc  = (const float*)d_in[13];
  const float* gn   = (const float*)d_in[14];
  const float* bn   = (const float*)d_in[15];
  const float* w1   = (const float*)d_in[16];
  const float* bw1  = (const float*)d_in[17];
  const float* w2   = (const float*)d_in[18];
  const float* bw2  = (const float*)d_in[19];
  const float* gf   = (const float*)d_in[20];
  const float* bfv  = (const float*)d_in[21];
  const float* g2   = (const float*)d_in[22];
  const float* b2   = (const float*)d_in[23];
  const int*   Eidx = (const int*)d_in[24];
  const int*   mask = (const int*)d_in[25];
  float* out = (float*)d_out;

  char* wsb = (char*)d_ws;
  size_t off = 0;
  auto alloc = [&](size_t bytes) -> void* {
    void* pp = wsb + off; off += (bytes + 255) & ~(size_t)255; return pp;
  };
  f16* hVb  = (f16*)alloc((size_t)M_*D_*2);
  f16* kbI  = (f16*)alloc((size_t)M_*D_*2);
  f16* vbI  = (f16*)alloc((size_t)M_*D_*2);
  f16* Wqb  = (f16*)alloc((size_t)D_*D_*2);
  f16* Wkb  = (f16*)alloc((size_t)D_*D_*2);
  f16* Wvb  = (f16*)alloc((size_t)D_*D_*2);
  f16* Wob  = (f16*)alloc((size_t)D_*(D_+ED_)*2);
  f16* w1b  = (f16*)alloc((size_t)DFF_*D_*2);
  f16* w2b  = (f16*)alloc((size_t)D_*DFF_*2);
  f16* qb   = (f16*)alloc((size_t)M_*D_*2);
  f16* kb   = (f16*)alloc((size_t)M_*D_*2);
  f16* vT   = (f16*)alloc((size_t)M_*D_*2);
  f16* biasT= (f16*)alloc((size_t)B_*T_*T_*2);
  f16* X2   = (f16*)alloc((size_t)M_*640*2);
  float* gpart = (float*)alloc((size_t)BH_*T_*KN*4);
  f16* hraw = (f16*)alloc((size_t)2*M_*D_*2);  // split-K partials (reused as ffraw)
  f16* hh   = (f16*)alloc((size_t)M_*D_*2);
  f16* ff1  = (f16*)alloc((size_t)M_*DFF_*2);
  if (ws_size < off) return;  // scratch insufficient -> loud validation failure
  f16* ffraw = hraw;

  // 1) fused prep: 9x fp32->f16 convert + fragment-tiled biasT (one launch)
  {
    CvtJobs J;
    const float* srcs[9] = {h_V, kin, vin, Wq, Wk, Wv, Wo, w1, w2};
    f16* dsts[9] = {hVb, kbI, vbI, Wqb, Wkb, Wvb, Wob, w1b, w2b};
    const int n4s[9] = {M_*D_/4, M_*D_/4, M_*D_/4, D_*D_/4, D_*D_/4, D_*D_/4,
                        D_*(D_+ED_)/4, DFF_*D_/4, D_*DFF_/4};
    int cum = 0;
    for (int i = 0; i < 9; ++i){
      J.s[i] = srcs[i]; J.d[i] = dsts[i]; J.start[i] = cum;
      cum += n4s[i]/256;
    }
    J.start[9] = cum;
    prep_kernel<<<cum + 2048,256,0,stream>>>(J, cum, bias, mask, tsc, biasT);
  }

  // 2) batched q/k/v projections, BK=64 pipelined (q pre-scaled; v -> vT)
  qkv_tile<<<384,256,0,stream>>>(hVb, kbI, vbI, Wqb, Wkb, Wvb, bq, bk, bv, tsc, qb, kb, vT);

  // 3) fused attention (QBLK=32, 3-slot ring), 1024 blocks x 512 thr
  attn_fused<<<1024,512,0,stream>>>(qb, kb, vT, biasT, Eidx, X2, gpart);

  // 4) edge embedding (sums 8 per-head partials)
  edge_kernel<<<M_,128,0,stream>>>(gpart, E, X2);

  // 5) out-proj split-K=2 (512 blocks) + residual LN (sums partials)
  gemm_n64<2,2><<<512,256,0,stream>>>(X2, Wob, bo, hraw, D_+ED_, D_, 8);
  ln1_kernel<<<M_,256,0,stream>>>(h_V, hraw, gn, bn, hh);

  // 6) FFN: FF1 gelu f16 (pipelined), FF2 split-K=2 (512 blocks)
  gemm_tile<1><<<512,256,0,stream>>>(hh, w1b, bw1, ff1, D_, DFF_, 16);
  gemm_n64<2,2><<<512,256,0,stream>>>(ff1, w2b, bw2, ffraw, DFF_, D_, 8);

  // 7) final double-LN (sums FF2 partials)
  final_kernel<<<M_,256,0,stream>>>(hh, ffraw, gf, bfv, g2, b2, out);
}

// Round 24
// 144.480 us; speedup vs baseline: 1.0085x; 1.0085x over previous
//
#include <hip/hip_runtime.h>
#include <hip/hip_fp16.h>
#include <math.h>

#define B_ 4
#define T_ 1024
#define D_ 512
#define H_ 8
#define HD_ 64
#define KN 30
#define ED_ 128
#define DFF_ 2048
#define M_ 4096   // B*T
#define BH_ 32

typedef _Float16 f16;
typedef __attribute__((ext_vector_type(8))) _Float16 f16x8;
typedef __attribute__((ext_vector_type(4))) _Float16 f16x4;
typedef __attribute__((ext_vector_type(4))) float f32x4;

#define MFMA16 __builtin_amdgcn_mfma_f32_16x16x32_f16
#define LOG2E 1.44269504088896f

__device__ __forceinline__ f16x8 ld8(const f16* p){ return *reinterpret_cast<const f16x8*>(p); }

__device__ __forceinline__ void gld16(const void* g, void* l){
  __builtin_amdgcn_global_load_lds((const __attribute__((address_space(1))) void*)g,
                                   (__attribute__((address_space(3))) void*)l, 16, 0, 0);
}

// ---------------- fused prep: 9x fp32->f16 convert + bias prep --------------
struct CvtJobs {
  const float* s[9];
  f16* d[9];
  int start[10];   // cumulative block starts; each block = 256 float4s
};

// blocks [0, cvtBlocks): convert; blocks [cvtBlocks, +2048): biasprep.
// biasT layout (QBLK=32): for (bi,tb,c,ws,qg,l16,l4), 8 f16 at u*8 =
// [step0 j0..3 | step1 j0..3] of scaled bias[t=tb*32+qg*16+l16]
// [s=c*128+ws*32+step*16+l4*4+j].
__global__ __launch_bounds__(256) void prep_kernel(
    CvtJobs J, int cvtBlocks,
    const float* __restrict__ bias, const int* __restrict__ mask,
    const float* __restrict__ tsc, f16* __restrict__ biasT)
{
  if (blockIdx.x < cvtBlocks){
    const int blk = blockIdx.x;
    int j = 0;
    while (j < 8 && blk >= J.start[j+1]) ++j;
    const int i = (blk - J.start[j])*256 + threadIdx.x;
    float4 v = reinterpret_cast<const float4*>(J.s[j])[i];
    union { f16 h[4]; ushort4 u; } o;
    o.h[0]=(f16)v.x; o.h[1]=(f16)v.y; o.h[2]=(f16)v.z; o.h[3]=(f16)v.w;
    reinterpret_cast<ushort4*>(J.d[j])[i] = o.u;
    return;
  }
  const int u = (blockIdx.x - cvtBlocks)*256 + threadIdx.x;   // 524288 threads
  const int l4 = u & 3, l16 = (u >> 2) & 15, qg = (u >> 6) & 1;
  const int ws = (u >> 7) & 3, c = (u >> 9) & 7, tb = (u >> 12) & 31, bi = u >> 17;
  const float s = exp2f(-2.0f*tanhf(tsc[0]))*LOG2E;  // log2e / 4^tanh(t)
  const int t  = tb*32 + qg*16 + l16;
  const int s0 = c*128 + ws*32 + l4*4;
  const float* bp = bias + ((size_t)bi*T_ + t)*T_ + s0;
  const int*   mp = mask + bi*T_ + s0;
  union { f16 h[8]; f16x8 v8; } o;
#pragma unroll
  for (int st = 0; st < 2; ++st){
    float4 v = *reinterpret_cast<const float4*>(bp + st*16);
    int4  mm = *reinterpret_cast<const int4*>(mp + st*16);
    float x[4] = {v.x,v.y,v.z,v.w};
    int  m4[4] = {mm.x,mm.y,mm.z,mm.w};
#pragma unroll
    for (int j = 0; j < 4; ++j){
      float tv = (x[j] + (m4[j] ? 0.f : -60000.f))*s;
      o.h[st*4 + j] = (f16)fmaxf(tv, -60000.f);
    }
  }
  *reinterpret_cast<f16x8*>(biasT + (size_t)u*8) = o.v8;
}

// =============== 128x64-tile GEMM, BK=64, pipelined, split-K ================
// KS slices: slice ks covers K range [ks*Kd/KS, +Kd/KS); writes partial f16
// at outp + ks*M*ldo (bias folded into slice 0 only). Consumer sums slices.
// EPI 1: gelu f16; EPI 2: raw f16. 3 blocks/CU (24 KB LDS, acc[4][2]).
template<int EPI, int KS>
__global__ __launch_bounds__(256,3) void gemm_n64(
    const f16* __restrict__ X, const f16* __restrict__ W,
    const float* __restrict__ bias, void* __restrict__ outp,
    int Kd, int ldo, int nbN)
{
  __shared__ f16 As[2*8192];   // 2 x [128][64]
  __shared__ f16 Bs[2*4096];   // 2 x [64][64]
  const int nwg = gridDim.x;
  const int bid = blockIdx.x;
  const int swz = (bid & 7)*(nwg >> 3) + (bid >> 3);
  const int per = nwg / KS;
  const int ks = swz / per;
  const int r2 = swz - ks*per;
  const int mb = r2 / nbN, nb = r2 - mb*nbN;
  const int rb = mb*128, cb = nb*64;
  const int kOff = ks*(Kd/KS);
  const int tid = threadIdx.x;
  const int w = tid >> 6, lane = tid & 63;
  const int l16 = lane & 15, l4 = lane >> 4;
  const int wr = w >> 1, wc = w & 1;
  const int key = l16 & 7;

  auto stage = [&](int ph, int slot){
#pragma unroll
    for (int i = 0; i < 4; ++i){
      const int cidx = i*256 + w*64 + lane;
      const int r = cidx >> 3, p = cidx & 7;
      gld16(X + (size_t)(rb + r)*Kd + kOff + ph*64 + ((p ^ (r & 7)) << 3),
            &As[slot*8192 + (i*256 + w*64)*8]);
    }
#pragma unroll
    for (int i = 0; i < 2; ++i){
      const int cidx = i*256 + w*64 + lane;
      const int r = cidx >> 3, p = cidx & 7;
      gld16(W + (size_t)(cb + r)*Kd + kOff + ph*64 + ((p ^ (r & 7)) << 3),
            &Bs[slot*4096 + (i*256 + w*64)*8]);
    }
  };

  f32x4 acc[4][2];
#pragma unroll
  for (int m = 0; m < 4; ++m)
#pragma unroll
    for (int n = 0; n < 2; ++n) acc[m][n] = (f32x4){0.f,0.f,0.f,0.f};

  const int nPh = (Kd/KS) >> 6;
  stage(0, 0);
  for (int ph = 0; ph < nPh; ++ph){
    if (ph < nPh-1) stage(ph+1, (ph+1)&1);
    if (ph < nPh-1) asm volatile("s_waitcnt vmcnt(6)" ::: "memory");
    else            asm volatile("s_waitcnt vmcnt(0)" ::: "memory");
    __builtin_amdgcn_sched_barrier(0);
    __builtin_amdgcn_s_barrier();
    __builtin_amdgcn_sched_barrier(0);
    const int baseA = (ph&1)*8192, baseB = (ph&1)*4096;
#pragma unroll
    for (int kk = 0; kk < 2; ++kk){
      f16x8 a[4], b[2];
#pragma unroll
      for (int m = 0; m < 4; ++m)
        a[m] = ld8(&As[baseA + (wr*64 + m*16 + l16)*64 + (((kk*4 + l4) ^ key) << 3)]);
#pragma unroll
      for (int n = 0; n < 2; ++n)
        b[n] = ld8(&Bs[baseB + (wc*32 + n*16 + l16)*64 + (((kk*4 + l4) ^ key) << 3)]);
#pragma unroll
      for (int m = 0; m < 4; ++m)
#pragma unroll
        for (int n = 0; n < 2; ++n)
          acc[m][n] = MFMA16(a[m], b[n], acc[m][n], 0,0,0);
    }
    __builtin_amdgcn_s_barrier();
  }

#pragma unroll
  for (int n = 0; n < 2; ++n){
    const int col = cb + wc*32 + n*16 + l16;
    const float bv = (ks == 0) ? bias[col] : 0.f;
#pragma unroll
    for (int m = 0; m < 4; ++m){
#pragma unroll
      for (int j = 0; j < 4; ++j){
        const int row = rb + wr*64 + m*16 + l4*4 + j;
        float v = acc[m][n][j] + bv;
        if (EPI == 1) v = 0.5f*v*(1.0f + erff(v*0.70710678118654752f));
        ((f16*)outp)[(size_t)ks*M_*ldo + (size_t)row*ldo + col] = (f16)v;
      }
    }
  }
}

// =============== batched QKV projection, 128x64 tiles, 3 blocks/CU ==========
// grid 768: gemm g in {q,k,v}, 256 blocks each (32 row x 8 col tiles).
// q folds 0.125*rtemp*log2e; v written pre-transposed vT[(b*H+h)*HD+dl][t].
__global__ __launch_bounds__(256,3) void qkv_n64(
    const f16* __restrict__ hV, const f16* __restrict__ kI, const f16* __restrict__ vI,
    const f16* __restrict__ Wq, const f16* __restrict__ Wk, const f16* __restrict__ Wv,
    const float* __restrict__ bq, const float* __restrict__ bk, const float* __restrict__ bv,
    const float* __restrict__ tsc,
    f16* __restrict__ qo, f16* __restrict__ ko, f16* __restrict__ vT)
{
  __shared__ f16 As[2*8192];   // 2 x [128][64]
  __shared__ f16 Bs[2*4096];   // 2 x [64][64]
  const int bid = blockIdx.x;
  const int swz = (bid & 7)*96 + (bid >> 3);
  const int g = swz >> 8;                 // 256 blocks per gemm
  const int r = swz & 255;
  const int mb = r >> 3, nb = r & 7;
  const f16* X  = (g == 0) ? hV : ((g == 1) ? kI : vI);
  const f16* W  = (g == 0) ? Wq : ((g == 1) ? Wk : Wv);
  const float* bias = (g == 0) ? bq : ((g == 1) ? bk : bv);
  const int rb = mb*128, cb = nb*64;
  const int tid = threadIdx.x;
  const int w = tid >> 6, lane = tid & 63;
  const int l16 = lane & 15, l4 = lane >> 4;
  const int wr = w >> 1, wc = w & 1;
  const int key = l16 & 7;

  auto stage = [&](int ph, int slot){
#pragma unroll
    for (int i = 0; i < 4; ++i){
      const int cidx = i*256 + w*64 + lane;
      const int rr = cidx >> 3, p = cidx & 7;
      gld16(X + (size_t)(rb + rr)*D_ + ph*64 + ((p ^ (rr & 7)) << 3),
            &As[slot*8192 + (i*256 + w*64)*8]);
    }
#pragma unroll
    for (int i = 0; i < 2; ++i){
      const int cidx = i*256 + w*64 + lane;
      const int rr = cidx >> 3, p = cidx & 7;
      gld16(W + (size_t)(cb + rr)*D_ + ph*64 + ((p ^ (rr & 7)) << 3),
            &Bs[slot*4096 + (i*256 + w*64)*8]);
    }
  };

  f32x4 acc[4][2];
#pragma unroll
  for (int m = 0; m < 4; ++m)
#pragma unroll
    for (int n = 0; n < 2; ++n) acc[m][n] = (f32x4){0.f,0.f,0.f,0.f};

  stage(0, 0);
#pragma unroll
  for (int ph = 0; ph < 8; ++ph){
    if (ph < 7) stage(ph+1, (ph+1)&1);
    if (ph < 7) asm volatile("s_waitcnt vmcnt(6)" ::: "memory");
    else        asm volatile("s_waitcnt vmcnt(0)" ::: "memory");
    __builtin_amdgcn_sched_barrier(0);
    __builtin_amdgcn_s_barrier();
    __builtin_amdgcn_sched_barrier(0);
    const int baseA = (ph&1)*8192, baseB = (ph&1)*4096;
#pragma unroll
    for (int kk = 0; kk < 2; ++kk){
      f16x8 a[4], b[2];
#pragma unroll
      for (int m = 0; m < 4; ++m)
        a[m] = ld8(&As[baseA + (wr*64 + m*16 + l16)*64 + (((kk*4 + l4) ^ key) << 3)]);
#pragma unroll
      for (int n = 0; n < 2; ++n)
        b[n] = ld8(&Bs[baseB + (wc*32 + n*16 + l16)*64 + (((kk*4 + l4) ^ key) << 3)]);
#pragma unroll
      for (int m = 0; m < 4; ++m)
#pragma unroll
        for (int n = 0; n < 2; ++n)
          acc[m][n] = MFMA16(a[m], b[n], acc[m][n], 0,0,0);
    }
    __builtin_amdgcn_s_barrier();
  }

  const float qs = exp2f(-2.0f*tanhf(tsc[0]))*LOG2E*0.125f;
  const float scale = (g == 0) ? qs : 1.0f;
  f16* out = (g == 0) ? qo : ko;
#pragma unroll
  for (int n = 0; n < 2; ++n){
    const int col = cb + wc*32 + n*16 + l16;
    const float bv = bias[col];
#pragma unroll
    for (int m = 0; m < 4; ++m){
#pragma unroll
      for (int j = 0; j < 4; ++j){
        const int row = rb + wr*64 + m*16 + l4*4 + j;
        const float v = (acc[m][n][j] + bv)*scale;
        if (g < 2){
          out[(size_t)row*D_ + col] = (f16)v;
        } else {
          const int b = row >> 10, t = row & (T_-1);
          const int h = col >> 6,  dl = col & (HD_-1);
          vT[(((size_t)b*H_ + h)*HD_ + dl)*T_ + t] = (f16)v;
        }
      }
    }
  }
}

// =============== fused attention (QBLK=32, 3-slot ring, depth-2) ============
// 8 waves: qg=w>>2 owns q-group, ws=w&3 owns s-subrange / d-cols.
// K/V staged through a 3-slot LDS ring: chunks c+1,c+2 in flight across each
// barrier (s_waitcnt vmcnt(4) mid-loop; 2 gld16/lane per stage). Bias
// fragments preloaded to registers; gather captured in regs, stored after.
__global__ __launch_bounds__(512,4) void attn_fused(
    const f16* __restrict__ q, const f16* __restrict__ k, const f16* __restrict__ vT,
    const f16* __restrict__ biasT, const int* __restrict__ eidx,
    f16* __restrict__ X2, float* __restrict__ gpart)
{
  __shared__ f16 Sb[3*8192];      // 48 KB: K/V chunk ring
  __shared__ f16 Pc[32*128];      // 8 KB: P chunk [32 q][128 s]
  const int bid = blockIdx.x;
  const int swz = (bid & 7)*128 + (bid >> 3);   // XCD-contiguous
  const int bh = swz >> 5, tb = swz & 31;
  const int bi = bh >> 3, h = bh & 7;
  const int t0 = tb*32;
  const int tid = threadIdx.x, w = tid >> 6, lane = tid & 63;
  const int qg = w >> 2, ws = w & 3;
  const int l16 = lane & 15, l4 = lane >> 4;
  const int key = l16 & 7;

  // ---- Q fragments ----
  const f16* qp = q + (size_t)(bi*T_ + t0 + qg*16 + l16)*D_ + h*HD_ + l4*8;
  const f16x8 q0 = ld8(qp), q1 = ld8(qp + 32);
  // ---- bias fragments: one f16x8 per chunk, preloaded ----
  const f16* bb = biasT + (size_t)(bi*32 + tb)*32768 + ws*1024 + qg*512 + l16*32 + l4*8;
  f16x8 bfr[8];
#pragma unroll
  for (int c = 0; c < 8; ++c) bfr[c] = ld8(bb + c*4096);
  // ---- gather tuples: each tid handles items of its own qg half ----
  const int tl = tid & 255;
  int ga_r, ga_kk, ga_id, gb_r = 0, gb_kk = 0, gb_id = -1;
  ga_r = tl/KN; ga_kk = tl - ga_r*KN;
  ga_id = eidx[((size_t)(bi*T_ + t0 + qg*16 + ga_r))*KN + ga_kk];
  if (tl + 256 < 16*KN){
    gb_r = (tl+256)/KN; gb_kk = (tl+256) - gb_r*KN;
    gb_id = eidx[((size_t)(bi*T_ + t0 + qg*16 + gb_r))*KN + gb_kk];
  }

  const f16* kg = k + (size_t)(bi*T_)*D_ + h*HD_;
  const f16* vg = vT + (size_t)bh*HD_*T_;

  auto stageK = [&](int c, int slot){
#pragma unroll
    for (int i = 0; i < 2; ++i){
      const int cidx = i*512 + w*64 + lane;
      const int r = cidx >> 3, p = cidx & 7;
      gld16(kg + (size_t)(c*128 + r)*D_ + ((p ^ (r & 7)) << 3),
            &Sb[slot*8192 + (i*512 + w*64)*8]);
    }
  };
  auto stageV = [&](int sc, int slot){
#pragma unroll
    for (int i = 0; i < 2; ++i){
      const int cidx = i*512 + w*64 + lane;
      const int r = cidx >> 4, p = cidx & 15;
      gld16(vg + (size_t)r*T_ + sc*128 + ((p ^ (r & 7)) << 3),
            &Sb[slot*8192 + (i*512 + w*64)*8]);
    }
  };

  // ---- QK^T: 8 chunks of 128 s; 3-slot ring, 2 chunks in flight ----
  f32x4 acc[16];
  stageK(0, 0);
  stageK(1, 1);
#pragma unroll
  for (int c = 0; c < 8; ++c){
    if (c < 6) stageK(c+2, (c+2)%3);
    if (c < 6)      asm volatile("s_waitcnt vmcnt(4)" ::: "memory");
    else if (c == 6) asm volatile("s_waitcnt vmcnt(2)" ::: "memory");
    else             asm volatile("s_waitcnt vmcnt(0)" ::: "memory");
    __builtin_amdgcn_sched_barrier(0);
    __builtin_amdgcn_s_barrier();
    __builtin_amdgcn_sched_barrier(0);
    const int base = (c%3)*8192;
#pragma unroll
    for (int step = 0; step < 2; ++step){
      const int rr = ws*32 + step*16 + l16;
      f32x4 a = {0.f,0.f,0.f,0.f};
      a = MFMA16(ld8(&Sb[base + rr*64 + ((l4 ^ key) << 3)]),       q0, a, 0,0,0);
      a = MFMA16(ld8(&Sb[base + rr*64 + (((4 + l4) ^ key) << 3)]), q1, a, 0,0,0);
#pragma unroll
      for (int j = 0; j < 4; ++j) a[j] += (float)bfr[c][step*4 + j];
      acc[c*2 + step] = a;
    }
    __builtin_amdgcn_s_barrier();   // readers of slot (c%3) done
  }

  // ---- softmax (stats overlay on idle Sb; sums redistributed via shfl) ----
  float* redf = (float*)Sb;         // [0..127]=max, [128..255]=sum
  float m = -3.4e38f;
#pragma unroll
  for (int c = 0; c < 16; ++c)
#pragma unroll
    for (int j = 0; j < 4; ++j) m = fmaxf(m, acc[c][j]);
  m = fmaxf(m, __shfl_xor(m, 16));
  m = fmaxf(m, __shfl_xor(m, 32));
  if (lane < 16) redf[(qg*4 + ws)*16 + lane] = m;
  __syncthreads();
  m = fmaxf(fmaxf(redf[(qg*4+0)*16 + l16], redf[(qg*4+1)*16 + l16]),
            fmaxf(redf[(qg*4+2)*16 + l16], redf[(qg*4+3)*16 + l16]));
  float l = 0.f;
#pragma unroll
  for (int c = 0; c < 16; ++c)
#pragma unroll
    for (int j = 0; j < 4; ++j){
      const float e = exp2f(acc[c][j] - m);
      l += e;
      acc[c][j] = e;                // acc now holds unnormalized P
    }
  l += __shfl_xor(l, 16);
  l += __shfl_xor(l, 32);
  if (lane < 16) redf[128 + (qg*4 + ws)*16 + lane] = l;
  __syncthreads();
  const float lrq = redf[128 + (qg*4+0)*16 + l16] + redf[128 + (qg*4+1)*16 + l16]
                  + redf[128 + (qg*4+2)*16 + l16] + redf[128 + (qg*4+3)*16 + l16];
  __syncthreads();                  // all lrq reads done before V staging clobbers
  const float lr_a = __shfl(lrq, ga_r);
  const float lr_b = __shfl(lrq, gb_r);

  // ---- PV: 8 chunks; 3-slot ring, 2 chunks in flight; gather -> regs ----
  f32x4 oo0 = {0.f,0.f,0.f,0.f}, oo1 = oo0, oo2 = oo0, oo3 = oo0;
  float pva = 0.f, pvb = 0.f;
  stageV(0, 0);
  stageV(1, 1);
#pragma unroll
  for (int sc = 0; sc < 8; ++sc){
    // write own P slice for chunk sc (Pc free: prior readers barrier'd)
#pragma unroll
    for (int step = 0; step < 2; ++step){
      const int slb = ws*32 + step*16 + l4*4;
      f16x4 pp;
#pragma unroll
      for (int j = 0; j < 4; ++j) pp[j] = (f16)acc[sc*2 + step][j];
      *reinterpret_cast<f16x4*>(
          &Pc[(qg*16 + l16)*128 + (((slb >> 3) ^ key) << 3) + (slb & 7)]) = pp;
    }
    if (sc < 6) stageV(sc+2, (sc+2)%3);
    if (sc < 6)      asm volatile("s_waitcnt vmcnt(4) lgkmcnt(0)" ::: "memory");
    else if (sc == 6) asm volatile("s_waitcnt vmcnt(2) lgkmcnt(0)" ::: "memory");
    else              asm volatile("s_waitcnt vmcnt(0) lgkmcnt(0)" ::: "memory");
    __builtin_amdgcn_sched_barrier(0);
    __builtin_amdgcn_s_barrier();
    __builtin_amdgcn_sched_barrier(0);
    const int base = (sc%3)*8192;
    const int vrow = (ws*16 + l16)*128;
#pragma unroll
    for (int grp = 0; grp < 4; ++grp){
      const int ch = (grp*4 + l4) ^ key;
      const f16x8 pa = ld8(&Pc[(qg*16 + l16)*128 + (ch << 3)]);
      const f16x8 vb = ld8(&Sb[base + vrow + (ch << 3)]);
      if (grp == 0)      oo0 = MFMA16(pa, vb, oo0, 0,0,0);
      else if (grp == 1) oo1 = MFMA16(pa, vb, oo1, 0,0,0);
      else if (grp == 2) oo2 = MFMA16(pa, vb, oo2, 0,0,0);
      else               oo3 = MFMA16(pa, vb, oo3, 0,0,0);
    }
    // edge gather capture (no VMEM stores inside the loop)
    if ((ga_id >> 7) == sc){
      const int r = qg*16 + ga_r;
      const int sl = ga_id & 127;
      pva = (float)Pc[r*128 + ((((sl >> 3) ^ (r & 7)) << 3) | (sl & 7))];
    }
    if (gb_id >= 0 && (gb_id >> 7) == sc){
      const int r = qg*16 + gb_r;
      const int sl = gb_id & 127;
      pvb = (float)Pc[r*128 + ((((sl >> 3) ^ (r & 7)) << 3) | (sl & 7))];
    }
    __builtin_amdgcn_s_barrier();   // readers of Pc + V slot (sc%3) done
  }
  const f32x4 o = (oo0 + oo1) + (oo2 + oo3);

  // ---- deferred gather stores ----
  gpart[((size_t)bh*T_ + t0 + qg*16 + ga_r)*KN + ga_kk] = pva/lr_a*0.125f;
  if (gb_id >= 0)
    gpart[((size_t)bh*T_ + t0 + qg*16 + gb_r)*KN + gb_kk] = pvb/lr_b*0.125f;

#pragma unroll
  for (int j = 0; j < 4; ++j){
    const float lr = __shfl(lrq, l4*4 + j);
    const int t = t0 + qg*16 + l4*4 + j;
    X2[((size_t)(bi*T_ + t))*640 + h*HD_ + ws*16 + l16] = (f16)(o[j]/lr);
  }
}

// ---------------- edge: weighted neighbor-embedding mean -------------------
// g[b,t,kk] = sum_h gpart[(b*H+h), t, kk]
__global__ __launch_bounds__(128) void edge_kernel(
    const float* __restrict__ gpart, const float* __restrict__ E, f16* __restrict__ X2)
{
  __shared__ float gl[KN];
  __shared__ float ginv;
  const int bt = blockIdx.x;          // b*T + t
  const int bi = bt >> 10, tt = bt & 1023;
  const int t = threadIdx.x;
  if (t < KN){
    float s = 0.f;
#pragma unroll
    for (int hh = 0; hh < H_; ++hh)
      s += gpart[((size_t)(bi*H_ + hh)*T_ + tt)*KN + t];
    gl[t] = s;
  }
  __syncthreads();
  if (t == 0){
    float s = 0.f;
#pragma unroll
    for (int i = 0; i < KN; ++i) s += gl[i];
    ginv = 1.0f/(s + 1e-6f);
  }
  __syncthreads();
  float acc = 0.f;
  const float* Ep = E + (size_t)bt*KN*ED_ + t;
#pragma unroll 5
  for (int kk = 0; kk < KN; ++kk) acc += gl[kk]*Ep[(size_t)kk*ED_];
  X2[(size_t)bt*640 + 512 + t] = (f16)(acc*ginv);
}

// ---------------- LayerNorm helpers ----------------------------------------
__device__ __forceinline__ float block_sum(float v, float* sbuf){
  for (int o = 32; o; o >>= 1) v += __shfl_down(v, o);
  __syncthreads();
  if ((threadIdx.x & 63) == 0) sbuf[threadIdx.x >> 6] = v;
  __syncthreads();
  return sbuf[0]+sbuf[1]+sbuf[2]+sbuf[3];
}

__global__ __launch_bounds__(256) void ln1_kernel(
    const float* __restrict__ hV, const f16* __restrict__ hraw,
    const float* __restrict__ gn, const float* __restrict__ bn,
    f16* __restrict__ hh)
{
  __shared__ float sbuf[4];
  const int r = blockIdx.x, t = threadIdx.x;
  const size_t base = (size_t)r*D_;
  const size_t MD = (size_t)M_*D_;
  float x0 = hV[base+t]     + (float)hraw[base+t]     + (float)hraw[MD+base+t];
  float x1 = hV[base+t+256] + (float)hraw[base+t+256] + (float)hraw[MD+base+t+256];
  float s = block_sum(x0+x1, sbuf);
  const float mean = s*(1.f/512.f);
  float d0 = x0-mean, d1 = x1-mean;
  float vs = block_sum(d0*d0+d1*d1, sbuf);
  const float rstd = rsqrtf(vs*(1.f/512.f) + 1e-5f);
  hh[base+t]     = (f16)(d0*rstd*gn[t]     + bn[t]);
  hh[base+t+256] = (f16)(d1*rstd*gn[t+256] + bn[t+256]);
}

__global__ __launch_bounds__(256) void final_kernel(
    const f16* __restrict__ hh, const f16* __restrict__ ffr,
    const float* __restrict__ gf, const float* __restrict__ bfv,
    const float* __restrict__ g2, const float* __restrict__ b2,
    float* __restrict__ out)
{
  __shared__ float sbuf[4];
  const int r = blockIdx.x, t = threadIdx.x;
  const size_t base = (size_t)r*D_;
  const size_t MD = (size_t)M_*D_;
  const float h0 = (float)hh[base+t], h1 = (float)hh[base+t+256];
  float x0 = h0 + (float)ffr[base+t]     + (float)ffr[MD+base+t];
  float x1 = h1 + (float)ffr[base+t+256] + (float)ffr[MD+base+t+256];
  float s = block_sum(x0+x1, sbuf);
  float mean = s*(1.f/512.f);
  float d0 = x0-mean, d1 = x1-mean;
  float vs = block_sum(d0*d0+d1*d1, sbuf);
  float rstd = rsqrtf(vs*(1.f/512.f) + 1e-6f);
  const float dh0 = d0*rstd*gf[t]     + bfv[t];
  const float dh1 = d1*rstd*gf[t+256] + bfv[t+256];
  const float y0 = h0 + dh0, y1 = h1 + dh1;
  s = block_sum(y0+y1, sbuf);
  mean = s*(1.f/512.f);
  d0 = y0-mean; d1 = y1-mean;
  vs = block_sum(d0*d0+d1*d1, sbuf);
  rstd = rsqrtf(vs*(1.f/512.f) + 1e-5f);
  out[base+t]     = d0*rstd*g2[t]     + b2[t];
  out[base+t+256] = d1*rstd*g2[t+256] + b2[t+256];
}

// ---------------------------------------------------------------------------
extern "C" void kernel_launch(void* const* d_in, const int* in_sizes, int n_in,
                              void* d_out, int out_size, void* d_ws, size_t ws_size,
                              hipStream_t stream)
{
  (void)in_sizes; (void)n_in; (void)out_size;
  const float* h_V  = (const float*)d_in[0];
  const float* kin  = (const float*)d_in[1];
  const float* vin  = (const float*)d_in[2];
  const float* E    = (const float*)d_in[3];
  const float* bias = (const float*)d_in[4];
  const float* Wq   = (const float*)d_in[5];
  const float* bq   = (const float*)d_in[6];
  const float* Wk   = (const float*)d_in[7];
  const float* bk   = (const float*)d_in[8];
  const float* Wv   = (const float*)d_in[9];
  const float* bv   = (const float*)d_in[10];
  const float* Wo   = (const float*)d_in[11];
  const float* bo   = (const float*)d_in[12];
  const float* tsc  = (const float*)d_in[13];
  const float* gn   = (const float*)d_in[14];
  const float* bn   = (const float*)d_in[15];
  const float* w1   = (const float*)d_in[16];
  const float* bw1  = (const float*)d_in[17];
  const float* w2   = (const float*)d_in[18];
  const float* bw2  = (const float*)d_in[19];
  const float* gf   = (const float*)d_in[20];
  const float* bfv  = (const float*)d_in[21];
  const float* g2   = (const float*)d_in[22];
  const float* b2   = (const float*)d_in[23];
  const int*   Eidx = (const int*)d_in[24];
  const int*   mask = (const int*)d_in[25];
  float* out = (float*)d_out;

  char* wsb = (char*)d_ws;
  size_t off = 0;
  auto alloc = [&](size_t bytes) -> void* {
    void* pp = wsb + off; off += (bytes + 255) & ~(size_t)255; return pp;
  };
  f16* hVb  = (f16*)alloc((size_t)M_*D_*2);
  f16* kbI  = (f16*)alloc((size_t)M_*D_*2);
  f16* vbI  = (f16*)alloc((size_t)M_*D_*2);
  f16* Wqb  = (f16*)alloc((size_t)D_*D_*2);
  f16* Wkb  = (f16*)alloc((size_t)D_*D_*2);
  f16* Wvb  = (f16*)alloc((size_t)D_*D_*2);
  f16* Wob  = (f16*)alloc((size_t)D_*(D_+ED_)*2);
  f16* w1b  = (f16*)alloc((size_t)DFF_*D_*2);
  f16* w2b  = (f16*)alloc((size_t)D_*DFF_*2);
  f16* qb   = (f16*)alloc((size_t)M_*D_*2);
  f16* kb   = (f16*)alloc((size_t)M_*D_*2);
  f16* vT   = (f16*)alloc((size_t)M_*D_*2);
  f16* biasT= (f16*)alloc((size_t)B_*T_*T_*2);
  f16* X2   = (f16*)alloc((size_t)M_*640*2);
  float* gpart = (float*)alloc((size_t)BH_*T_*KN*4);
  f16* hraw = (f16*)alloc((size_t)2*M_*D_*2);  // split-K partials (reused as ffraw)
  f16* hh   = (f16*)alloc((size_t)M_*D_*2);
  f16* ff1  = (f16*)alloc((size_t)M_*DFF_*2);
  if (ws_size < off) return;  // scratch insufficient -> loud validation failure
  f16* ffraw = hraw;

  // 1) fused prep: 9x fp32->f16 convert + fragment-tiled biasT (one launch)
  {
    CvtJobs J;
    const float* srcs[9] = {h_V, kin, vin, Wq, Wk, Wv, Wo, w1, w2};
    f16* dsts[9] = {hVb, kbI, vbI, Wqb, Wkb, Wvb, Wob, w1b, w2b};
    const int n4s[9] = {M_*D_/4, M_*D_/4, M_*D_/4, D_*D_/4, D_*D_/4, D_*D_/4,
                        D_*(D_+ED_)/4, DFF_*D_/4, D_*DFF_/4};
    int cum = 0;
    for (int i = 0; i < 9; ++i){
      J.s[i] = srcs[i]; J.d[i] = dsts[i]; J.start[i] = cum;
      cum += n4s[i]/256;
    }
    J.start[9] = cum;
    prep_kernel<<<cum + 2048,256,0,stream>>>(J, cum, bias, mask, tsc, biasT);
  }

  // 2) batched q/k/v projections, 128x64 tiles, 3 blocks/CU (768 blocks)
  qkv_n64<<<768,256,0,stream>>>(hVb, kbI, vbI, Wqb, Wkb, Wvb, bq, bk, bv, tsc, qb, kb, vT);

  // 3) fused attention (QBLK=32, 3-slot ring), 1024 blocks x 512 thr
  attn_fused<<<1024,512,0,stream>>>(qb, kb, vT, biasT, Eidx, X2, gpart);

  // 4) edge embedding (sums 8 per-head partials)
  edge_kernel<<<M_,128,0,stream>>>(gpart, E, X2);

  // 5) out-proj split-K=2 (512 blocks) + residual LN (sums partials)
  gemm_n64<2,2><<<512,256,0,stream>>>(X2, Wob, bo, hraw, D_+ED_, D_, 8);
  ln1_kernel<<<M_,256,0,stream>>>(h_V, hraw, gn, bn, hh);

  // 6) FFN: FF1 gelu 128x64 tiles (1024 blocks, 3/CU), FF2 split-K=2
  gemm_n64<1,1><<<1024,256,0,stream>>>(hh, w1b, bw1, ff1, D_, DFF_, 32);
  gemm_n64<2,2><<<512,256,0,stream>>>(ff1, w2b, bw2, ffraw, DFF_, D_, 8);

  // 7) final double-LN (sums FF2 partials)
  final_kernel<<<M_,256,0,stream>>>(hh, ffraw, gf, bfv, g2, b2, out);
}